// Round 5
// baseline (1785.726 us; speedup 1.0000x reference)
//
#include <hip/hip_runtime.h>
#include <cstdint>
#include <cstddef>

constexpr int Lc = 2, Ec = 8, Hc = 1024, Ic = 2048, Tc = 2048;

typedef __bf16 bf16x8 __attribute__((ext_vector_type(8)));
typedef float f32x4 __attribute__((ext_vector_type(4)));

__device__ __forceinline__ unsigned short f2bf(float f) {
  unsigned u = __builtin_bit_cast(unsigned, f);
  u = (u + 0x7fffu + ((u >> 16) & 1u)) >> 16;
  return (unsigned short)u;
}
__device__ __forceinline__ float bf2f(unsigned short h) {
  unsigned u = (unsigned)h << 16;
  return __builtin_bit_cast(float, u);
}
__device__ __forceinline__ bf16x8 ldfrag(const unsigned short* p) {
  return __builtin_bit_cast(bf16x8, *(const uint4*)p);
}
__device__ __forceinline__ bf16x8 ldfragG(const unsigned short* p) {
  return __builtin_bit_cast(bf16x8, *(const uint4*)p);
}
// async global->LDS, 16B/lane; LDS dest = wave-uniform base + lane*16 (linear)
__device__ __forceinline__ void gl2lds(const unsigned short* g, void* lds) {
  __builtin_amdgcn_global_load_lds(
      (const __attribute__((address_space(1))) void*)g,
      (__attribute__((address_space(3))) void*)lds, 16, 0, 0);
}

// ---------------- router + fp32->(hi,lo) bf16 convert (fused) ----------------
__global__ __launch_bounds__(256) void router_kernel(
    const float* __restrict__ x, const float* __restrict__ rw, float* __restrict__ logits,
    unsigned short* __restrict__ xh, unsigned short* __restrict__ xl) {
  const int t = blockIdx.x;
  const int tid = threadIdx.x;
  const float* xr = x + (size_t)t * Hc;
  const int h0 = tid * 4;
  const float4 v = *(const float4*)(xr + h0);
  const float f[4] = {v.x, v.y, v.z, v.w};
  unsigned short hs[4], ls[4];
#pragma unroll
  for (int j = 0; j < 4; ++j) {
    hs[j] = f2bf(f[j]);
    ls[j] = f2bf(f[j] - bf2f(hs[j]));
  }
  *(uint2*)(xh + (size_t)t * Hc + h0) =
      uint2{(unsigned)hs[0] | ((unsigned)hs[1] << 16), (unsigned)hs[2] | ((unsigned)hs[3] << 16)};
  *(uint2*)(xl + (size_t)t * Hc + h0) =
      uint2{(unsigned)ls[0] | ((unsigned)ls[1] << 16), (unsigned)ls[2] | ((unsigned)ls[3] << 16)};

  float acc[Ec];
#pragma unroll
  for (int e = 0; e < Ec; ++e) acc[e] = 0.f;
#pragma unroll
  for (int j = 0; j < 4; ++j) {
    const float* w = rw + (size_t)(h0 + j) * Ec;
#pragma unroll
    for (int e = 0; e < Ec; ++e) acc[e] += f[j] * w[e];
  }
  __shared__ float red[256][Ec];
#pragma unroll
  for (int e = 0; e < Ec; ++e) red[tid][e] = acc[e];
  __syncthreads();
  for (int s = 128; s > 0; s >>= 1) {
    if (tid < s) {
#pragma unroll
      for (int e = 0; e < Ec; ++e) red[tid][e] += red[tid + s][e];
    }
    __syncthreads();
  }
  if (tid < Ec) logits[(size_t)t * Ec + tid] = red[0][tid];
}

// ---------------- top-2 ----------------
__global__ void topk_kernel(const float* __restrict__ logits, int* __restrict__ cnt,
                            int* __restrict__ tokList, float* __restrict__ wList) {
  const int t = blockIdx.x * blockDim.x + threadIdx.x;
  if (t >= Tc) return;
  float l[Ec];
#pragma unroll
  for (int e = 0; e < Ec; ++e) l[e] = logits[(size_t)t * Ec + e];
  float b0 = -3.4e38f, b1 = -3.4e38f;
  int i0 = 0, i1 = 0;
#pragma unroll
  for (int e = 0; e < Ec; ++e) {
    if (l[e] > b0) { b1 = b0; i1 = i0; b0 = l[e]; i0 = e; }
    else if (l[e] > b1) { b1 = l[e]; i1 = e; }
  }
  const float w0 = 1.f / (1.f + expf(b1 - b0));
  const float w1 = 1.f - w0;
  int p0 = atomicAdd(&cnt[i0], 1);
  tokList[i0 * Tc + p0] = t;
  wList[i0 * Tc + p0] = w0;
  int p1 = atomicAdd(&cnt[i1], 1);
  tokList[i1 * Tc + p1] = t;
  wList[i1 * Tc + p1] = w1;
}

__global__ void offsets_kernel(const int* __restrict__ cnt, int* __restrict__ off) {
  if (threadIdx.x == 0) {
    int s = 0;
    for (int e = 0; e < Ec; ++e) { off[e] = s; s += cnt[e]; }
  }
}

// ---------------- weight convert into STAGED-TILE order ----------------
// fp32 [E][K][N] -> bf16 staged [e][nb=N/64][ks=K/32][q=4][n=64][j=8]; chunk = 4KB.
template <bool SPLIT>
__global__ __launch_bounds__(256) void wconv_kernel(const float* __restrict__ src,
                                                    unsigned short* __restrict__ dh,
                                                    unsigned short* __restrict__ dl,
                                                    int K, int N) {
  const int e = blockIdx.z;
  const int n0 = blockIdx.x * 64;
  const int k0 = blockIdx.y * 64;
  const int NB = N >> 6, KS = K >> 5;
  src += (size_t)e * K * N;

  __shared__ unsigned short lh[64][66];
  __shared__ unsigned short ll[SPLIT ? 64 : 1][66];
  const int tid = threadIdx.x;

  {
    const int r = tid >> 2, cg = (tid & 3) * 16;
    const float* sp = src + (size_t)(k0 + r) * N + n0 + cg;
#pragma unroll
    for (int i = 0; i < 16; i += 4) {
      const float4 v = *(const float4*)(sp + i);
      const float f[4] = {v.x, v.y, v.z, v.w};
#pragma unroll
      for (int j = 0; j < 4; ++j) {
        const unsigned short h = f2bf(f[j]);
        lh[r][cg + i + j] = h;
        if constexpr (SPLIT) ll[r][cg + i + j] = f2bf(f[j] - bf2f(h));
      }
    }
  }
  __syncthreads();
  {
    const int ksl = tid >> 7, q = (tid >> 5) & 3, n2 = (tid & 31) * 2;
    const int kb = ksl * 32 + q * 8;
    union { unsigned short s[16]; uint4 u[2]; } oh, ol;
#pragma unroll
    for (int s = 0; s < 2; ++s)
#pragma unroll
      for (int i = 0; i < 8; ++i) {
        oh.s[s * 8 + i] = lh[kb + i][n2 + s];
        if constexpr (SPLIT) ol.s[s * 8 + i] = ll[kb + i][n2 + s];
      }
    const size_t cb =
        (((size_t)e * NB + (n0 >> 6)) * KS + (k0 >> 5) + ksl) * 2048 + q * 512 + n2 * 8;
    *(uint4*)(dh + cb) = oh.u[0];
    *(uint4*)(dh + cb + 8) = oh.u[1];
    if constexpr (SPLIT) {
      *(uint4*)(dl + cb) = ol.u[0];
      *(uint4*)(dl + cb + 8) = ol.u[1];
    }
  }
}

// ---------------- gate_up GEMM: BM=128, BN=64(g)+64(u), BK=32 ----------------
// B: staged chunks via gl2lds 2-phase dbuf. A: fragments DIRECT global->VGPR, reg-dbuf.
template <bool SPLIT>
__global__ __launch_bounds__(256, SPLIT ? 2 : 3) void gateup_kernel(
    const unsigned short* __restrict__ xh, const unsigned short* __restrict__ xl,
    const unsigned short* __restrict__ gwSh, const unsigned short* __restrict__ gwSl,
    const int* __restrict__ cnt, const int* __restrict__ off,
    const int* __restrict__ tokList, unsigned short* __restrict__ actH,
    unsigned short* __restrict__ actL) {
  // bijective chunked XCD swizzle (grid % 8 == 0): mi fastest, e middle, nb slowest
  const int d = blockIdx.x;
  const int lid = (d & 7) * ((int)gridDim.x >> 3) + (d >> 3);
  const int mi = lid & 15;
  const int e = (lid >> 4) & 7;
  const int nb = lid >> 7;  // 0..31
  const int M = cnt[e];
  const int m0 = mi * 128;
  if (m0 >= M) return;
  const int tid = threadIdx.x;
  const int wv = tid >> 6, l64 = tid & 63;
  const int q = l64 >> 4, mr = l64 & 15;
  const int nc = wv * 16 + mr;
  const int wvo = wv * 1024;

  __shared__ __align__(16) unsigned short sBgh[2][2048];
  __shared__ __align__(16) unsigned short sBgl[2][SPLIT ? 2048 : 8];
  __shared__ __align__(16) unsigned short sBuh[2][2048];
  __shared__ __align__(16) unsigned short sBul[2][SPLIT ? 2048 : 8];

  const size_t gBase = (((size_t)e * 64 + nb) * 32) * 2048 + tid * 8;
  const size_t uBase = (((size_t)e * 64 + nb + 32) * 32) * 2048 + tid * 8;

  // per-lane A fragment element-offsets (8 m-tiles)
  unsigned aoff[8];
#pragma unroll
  for (int mt = 0; mt < 8; ++mt) {
    int r = m0 + mt * 16 + mr;
    if (r >= M) r = M - 1;
    aoff[mt] = (unsigned)tokList[e * Tc + r] * Hc + q * 8;
  }

  f32x4 accg[8], accu[8];
#pragma unroll
  for (int i = 0; i < 8; ++i) {
    accg[i] = f32x4{0.f, 0.f, 0.f, 0.f};
    accu[i] = f32x4{0.f, 0.f, 0.f, 0.f};
  }

  bf16x8 ah0[8], al0[8], ah1[8], al1[8];
  // prologue: A frags for ks=0, B chunk 0
#pragma unroll
  for (int mt = 0; mt < 8; ++mt) {
    ah0[mt] = ldfragG(xh + aoff[mt]);
    if constexpr (SPLIT) al0[mt] = ldfragG(xl + aoff[mt]);
  }
  gl2lds(gwSh + gBase, (char*)sBgh[0] + wvo);
  gl2lds(gwSh + uBase, (char*)sBuh[0] + wvo);
  if constexpr (SPLIT) {
    gl2lds(gwSl + gBase, (char*)sBgl[0] + wvo);
    gl2lds(gwSl + uBase, (char*)sBul[0] + wvo);
  }
  __syncthreads();

#define GU_STEP(CU, NX, AH, AL, AHN, ALN, KS)                                           \
  {                                                                                     \
    if ((KS) + 1 < 32) {                                                                \
      gl2lds(gwSh + gBase + (size_t)((KS) + 1) * 2048, (char*)sBgh[NX] + wvo);          \
      gl2lds(gwSh + uBase + (size_t)((KS) + 1) * 2048, (char*)sBuh[NX] + wvo);          \
      if constexpr (SPLIT) {                                                            \
        gl2lds(gwSl + gBase + (size_t)((KS) + 1) * 2048, (char*)sBgl[NX] + wvo);        \
        gl2lds(gwSl + uBase + (size_t)((KS) + 1) * 2048, (char*)sBul[NX] + wvo);        \
      }                                                                                 \
      _Pragma("unroll")                                                                 \
      for (int mt = 0; mt < 8; ++mt) {                                                  \
        AHN[mt] = ldfragG(xh + aoff[mt] + ((KS) + 1) * 32);                             \
        if constexpr (SPLIT) ALN[mt] = ldfragG(xl + aoff[mt] + ((KS) + 1) * 32);        \
      }                                                                                 \
    }                                                                                   \
    const bf16x8 bghf = ldfrag(&sBgh[CU][(q * 64 + nc) * 8]);                           \
    const bf16x8 buhf = ldfrag(&sBuh[CU][(q * 64 + nc) * 8]);                           \
    _Pragma("unroll")                                                                   \
    for (int mt = 0; mt < 8; ++mt) {                                                    \
      accg[mt] = __builtin_amdgcn_mfma_f32_16x16x32_bf16(AH[mt], bghf, accg[mt], 0, 0, 0); \
      accu[mt] = __builtin_amdgcn_mfma_f32_16x16x32_bf16(AH[mt], buhf, accu[mt], 0, 0, 0); \
    }                                                                                   \
    if constexpr (SPLIT) {                                                              \
      const bf16x8 bglf = ldfrag(&sBgl[CU][(q * 64 + nc) * 8]);                         \
      const bf16x8 bulf = ldfrag(&sBul[CU][(q * 64 + nc) * 8]);                         \
      _Pragma("unroll")                                                                 \
      for (int mt = 0; mt < 8; ++mt) {                                                  \
        accg[mt] = __builtin_amdgcn_mfma_f32_16x16x32_bf16(AH[mt], bglf, accg[mt], 0, 0, 0); \
        accu[mt] = __builtin_amdgcn_mfma_f32_16x16x32_bf16(AH[mt], bulf, accu[mt], 0, 0, 0); \
      }                                                                                 \
      _Pragma("unroll")                                                                 \
      for (int mt = 0; mt < 8; ++mt) {                                                  \
        accg[mt] = __builtin_amdgcn_mfma_f32_16x16x32_bf16(AL[mt], bghf, accg[mt], 0, 0, 0); \
        accu[mt] = __builtin_amdgcn_mfma_f32_16x16x32_bf16(AL[mt], buhf, accu[mt], 0, 0, 0); \
      }                                                                                 \
    }                                                                                   \
    __syncthreads();                                                                    \
  }

  for (int ks = 0; ks < 32; ks += 2) {
    GU_STEP(0, 1, ah0, al0, ah1, al1, ks)
    GU_STEP(1, 0, ah1, al1, ah0, al0, ks + 1)
  }
#undef GU_STEP

  const int valid = M - m0;
  const int rowbase = off[e] + m0;
#pragma unroll
  for (int mt = 0; mt < 8; ++mt) {
#pragma unroll
    for (int r = 0; r < 4; ++r) {
      const int row = mt * 16 + q * 4 + r;  // C/D: row=(lane>>4)*4+reg, col=lane&15 (m89)
      if (row < valid) {
        const float g = accg[mt][r];
        const float u = accu[mt][r];
        const float a = (g / (1.f + expf(-g))) * u;
        const size_t idx = (size_t)(rowbase + row) * Ic + (nb * 64 + nc);
        const unsigned short h = f2bf(a);
        actH[idx] = h;
        if constexpr (SPLIT) actL[idx] = f2bf(a - bf2f(h));
      }
    }
  }
}

// ---------------- down GEMM: BM=128, BN=64, K=Ic ----------------
template <bool SPLIT>
__global__ __launch_bounds__(256, SPLIT ? 2 : 3) void down_kernel(
    const unsigned short* __restrict__ actH, const unsigned short* __restrict__ actL,
    const unsigned short* __restrict__ dwSh, const unsigned short* __restrict__ dwSl,
    const int* __restrict__ cnt, const int* __restrict__ off,
    const int* __restrict__ tokList, const float* __restrict__ wList,
    float* __restrict__ out) {
  const int d = blockIdx.x;
  const int lid = (d & 7) * ((int)gridDim.x >> 3) + (d >> 3);
  const int mi = lid & 15;
  const int e = (lid >> 4) & 7;
  const int nb = lid >> 7;  // 0..15
  const int M = cnt[e];
  const int m0 = mi * 128;
  if (m0 >= M) return;
  const int tid = threadIdx.x;
  const int wv = tid >> 6, l64 = tid & 63;
  const int q = l64 >> 4, mr = l64 & 15;
  const int nc = wv * 16 + mr;
  const int wvo = wv * 1024;

  __shared__ __align__(16) unsigned short sBh[2][2048];
  __shared__ __align__(16) unsigned short sBl[2][SPLIT ? 2048 : 8];
  __shared__ int sTok[128];
  __shared__ float sW[128];

  if (tid < 128) {
    int r = m0 + tid;
    int rc = r < M ? r : M - 1;
    sTok[tid] = tokList[e * Tc + rc];
    sW[tid] = wList[e * Tc + rc];
  }

  const size_t bBase = (((size_t)e * 16 + nb) * 64) * 2048 + tid * 8;
  const int offE = off[e];

  unsigned aoff[8];
#pragma unroll
  for (int mt = 0; mt < 8; ++mt) {
    int r = m0 + mt * 16 + mr;
    if (r >= M) r = M - 1;
    aoff[mt] = (unsigned)(offE + r) * Ic + q * 8;
  }

  f32x4 acc[8];
#pragma unroll
  for (int i = 0; i < 8; ++i) acc[i] = f32x4{0.f, 0.f, 0.f, 0.f};

  bf16x8 ah0[8], al0[8], ah1[8], al1[8];
#pragma unroll
  for (int mt = 0; mt < 8; ++mt) {
    ah0[mt] = ldfragG(actH + aoff[mt]);
    if constexpr (SPLIT) al0[mt] = ldfragG(actL + aoff[mt]);
  }
  gl2lds(dwSh + bBase, (char*)sBh[0] + wvo);
  if constexpr (SPLIT) gl2lds(dwSl + bBase, (char*)sBl[0] + wvo);
  __syncthreads();

#define DN_STEP(CU, NX, AH, AL, AHN, ALN, KS)                                           \
  {                                                                                     \
    if ((KS) + 1 < 64) {                                                                \
      gl2lds(dwSh + bBase + (size_t)((KS) + 1) * 2048, (char*)sBh[NX] + wvo);           \
      if constexpr (SPLIT)                                                              \
        gl2lds(dwSl + bBase + (size_t)((KS) + 1) * 2048, (char*)sBl[NX] + wvo);         \
      _Pragma("unroll")                                                                 \
      for (int mt = 0; mt < 8; ++mt) {                                                  \
        AHN[mt] = ldfragG(actH + aoff[mt] + ((KS) + 1) * 32);                           \
        if constexpr (SPLIT) ALN[mt] = ldfragG(actL + aoff[mt] + ((KS) + 1) * 32);      \
      }                                                                                 \
    }                                                                                   \
    const bf16x8 bh = ldfrag(&sBh[CU][(q * 64 + nc) * 8]);                              \
    _Pragma("unroll")                                                                   \
    for (int mt = 0; mt < 8; ++mt)                                                      \
      acc[mt] = __builtin_amdgcn_mfma_f32_16x16x32_bf16(AH[mt], bh, acc[mt], 0, 0, 0);  \
    if constexpr (SPLIT) {                                                              \
      const bf16x8 bl = ldfrag(&sBl[CU][(q * 64 + nc) * 8]);                            \
      _Pragma("unroll")                                                                 \
      for (int mt = 0; mt < 8; ++mt)                                                    \
        acc[mt] = __builtin_amdgcn_mfma_f32_16x16x32_bf16(AH[mt], bl, acc[mt], 0, 0, 0);\
      _Pragma("unroll")                                                                 \
      for (int mt = 0; mt < 8; ++mt)                                                    \
        acc[mt] = __builtin_amdgcn_mfma_f32_16x16x32_bf16(AL[mt], bh, acc[mt], 0, 0, 0);\
    }                                                                                   \
    __syncthreads();                                                                    \
  }

  for (int ks = 0; ks < 64; ks += 2) {
    DN_STEP(0, 1, ah0, al0, ah1, al1, ks)
    DN_STEP(1, 0, ah1, al1, ah0, al0, ks + 1)
  }
#undef DN_STEP

  const int valid = M - m0;
#pragma unroll
  for (int mt = 0; mt < 8; ++mt) {
#pragma unroll
    for (int r = 0; r < 4; ++r) {
      const int row = mt * 16 + q * 4 + r;
      if (row < valid) {
        atomicAdd(&out[(size_t)sTok[row] * Hc + (nb * 64 + nc)], sW[row] * acc[mt][r]);
      }
    }
  }
}

// ---------------- host ----------------
extern "C" void kernel_launch(void* const* d_in, const int* in_sizes, int n_in, void* d_out,
                              int out_size, void* d_ws, size_t ws_size, hipStream_t stream) {
  const float* x_in = (const float*)d_in[0];
  const float* rw = (const float*)d_in[1];
  const float* guw = (const float*)d_in[2];
  const float* dnw = (const float*)d_in[3];
  float* out = (float*)d_out;
  float* logits_base = out + (size_t)Tc * Hc;

  uint8_t* w = (uint8_t*)d_ws;
  float* x1 = (float*)w;                    w += (size_t)Tc * Hc * 4;
  unsigned short* xh = (unsigned short*)w;  w += (size_t)Tc * Hc * 2;
  unsigned short* xl = (unsigned short*)w;  w += (size_t)Tc * Hc * 2;
  unsigned short* actH = (unsigned short*)w; w += (size_t)Tc * 2 * Ic * 2;
  unsigned short* actL = (unsigned short*)w; w += (size_t)Tc * 2 * Ic * 2;
  int* tokList = (int*)w;                   w += (size_t)Ec * Tc * 4;
  float* wList = (float*)w;                 w += (size_t)Ec * Tc * 4;
  int* cnt0 = (int*)w;                      w += 64;
  int* cnt1 = (int*)w;                      w += 64;
  int* off = (int*)w;                       w += 64;
  unsigned short* wTh = (unsigned short*)w; w += (size_t)Ec * 2 * Ic * Hc * 2;
  unsigned short* wTl = (unsigned short*)w; w += (size_t)Ec * 2 * Ic * Hc * 2;

  hipMemsetAsync(cnt0, 0, 192, stream);
  hipMemsetAsync(x1, 0, (size_t)Tc * Hc * 4, stream);
  hipMemsetAsync(out, 0, (size_t)Tc * Hc * 4, stream);

  // ---- layer 0 (split-bf16 precision) ----
  router_kernel<<<Tc, 256, 0, stream>>>(x_in, rw, logits_base, xh, xl);
  topk_kernel<<<Tc / 256, 256, 0, stream>>>(logits_base, cnt0, tokList, wList);
  offsets_kernel<<<1, 64, 0, stream>>>(cnt0, off);
  wconv_kernel<true><<<dim3(2 * Ic / 64, Hc / 64, Ec), 256, 0, stream>>>(guw, wTh, wTl, Hc, 2 * Ic);
  gateup_kernel<true><<<16 * 32 * Ec, 256, 0, stream>>>(xh, xl, wTh, wTl, cnt0, off,
                                                        tokList, actH, actL);
  wconv_kernel<true><<<dim3(Hc / 64, Ic / 64, Ec), 256, 0, stream>>>(dnw, wTh, wTl, Ic, Hc);
  down_kernel<true><<<16 * 16 * Ec, 256, 0, stream>>>(actH, actL, wTh, wTl, cnt0,
                                                      off, tokList, wList, x1);

  // ---- layer 1 (plain bf16) ----
  const float* rw1 = rw + (size_t)Hc * Ec;
  const float* guw1 = guw + (size_t)Ec * Hc * 2 * Ic;
  const float* dnw1 = dnw + (size_t)Ec * Ic * Hc;
  router_kernel<<<Tc, 256, 0, stream>>>(x1, rw1, logits_base + (size_t)Tc * Ec, xh, xl);
  topk_kernel<<<Tc / 256, 256, 0, stream>>>(logits_base + (size_t)Tc * Ec, cnt1, tokList, wList);
  offsets_kernel<<<1, 64, 0, stream>>>(cnt1, off);
  wconv_kernel<false><<<dim3(2 * Ic / 64, Hc / 64, Ec), 256, 0, stream>>>(guw1, wTh, wTl, Hc, 2 * Ic);
  gateup_kernel<false><<<16 * 32 * Ec, 256, 0, stream>>>(xh, xl, wTh, wTl, cnt1, off,
                                                         tokList, actH, actL);
  wconv_kernel<false><<<dim3(Hc / 64, Ic / 64, Ec), 256, 0, stream>>>(dnw1, wTh, wTl, Ic, Hc);
  down_kernel<false><<<16 * 16 * Ec, 256, 0, stream>>>(actH, actL, wTh, wTl, cnt1,
                                                       off, tokList, wList, out);
}

// Round 6
// 1066.375 us; speedup vs baseline: 1.6746x; 1.6746x over previous
//
#include <hip/hip_runtime.h>
#include <cstdint>
#include <cstddef>

constexpr int Lc = 2, Ec = 8, Hc = 1024, Ic = 2048, Tc = 2048;

typedef __bf16 bf16x8 __attribute__((ext_vector_type(8)));
typedef float f32x4 __attribute__((ext_vector_type(4)));

__device__ __forceinline__ unsigned short f2bf(float f) {
  unsigned u = __builtin_bit_cast(unsigned, f);
  u = (u + 0x7fffu + ((u >> 16) & 1u)) >> 16;
  return (unsigned short)u;
}
__device__ __forceinline__ float bf2f(unsigned short h) {
  unsigned u = (unsigned)h << 16;
  return __builtin_bit_cast(float, u);
}
__device__ __forceinline__ bf16x8 ldfrag(const unsigned short* p) {
  return __builtin_bit_cast(bf16x8, *(const uint4*)p);
}
// async global->LDS, 16B/lane; LDS dest = wave-uniform base + lane*16 (linear)
__device__ __forceinline__ void gl2lds(const unsigned short* g, void* lds) {
  __builtin_amdgcn_global_load_lds(
      (const __attribute__((address_space(1))) void*)g,
      (__attribute__((address_space(3))) void*)lds, 16, 0, 0);
}

// ---------------- router + fp32->(hi,lo) bf16 convert (fused) ----------------
__global__ __launch_bounds__(256) void router_kernel(
    const float* __restrict__ x, const float* __restrict__ rw, float* __restrict__ logits,
    unsigned short* __restrict__ xh, unsigned short* __restrict__ xl) {
  const int t = blockIdx.x;
  const int tid = threadIdx.x;
  const float* xr = x + (size_t)t * Hc;
  const int h0 = tid * 4;
  const float4 v = *(const float4*)(xr + h0);
  const float f[4] = {v.x, v.y, v.z, v.w};
  unsigned short hs[4], ls[4];
#pragma unroll
  for (int j = 0; j < 4; ++j) {
    hs[j] = f2bf(f[j]);
    ls[j] = f2bf(f[j] - bf2f(hs[j]));
  }
  *(uint2*)(xh + (size_t)t * Hc + h0) =
      uint2{(unsigned)hs[0] | ((unsigned)hs[1] << 16), (unsigned)hs[2] | ((unsigned)hs[3] << 16)};
  *(uint2*)(xl + (size_t)t * Hc + h0) =
      uint2{(unsigned)ls[0] | ((unsigned)ls[1] << 16), (unsigned)ls[2] | ((unsigned)ls[3] << 16)};

  float acc[Ec];
#pragma unroll
  for (int e = 0; e < Ec; ++e) acc[e] = 0.f;
#pragma unroll
  for (int j = 0; j < 4; ++j) {
    const float* w = rw + (size_t)(h0 + j) * Ec;
#pragma unroll
    for (int e = 0; e < Ec; ++e) acc[e] += f[j] * w[e];
  }
  __shared__ float red[256][Ec];
#pragma unroll
  for (int e = 0; e < Ec; ++e) red[tid][e] = acc[e];
  __syncthreads();
  for (int s = 128; s > 0; s >>= 1) {
    if (tid < s) {
#pragma unroll
      for (int e = 0; e < Ec; ++e) red[tid][e] += red[tid + s][e];
    }
    __syncthreads();
  }
  if (tid < Ec) logits[(size_t)t * Ec + tid] = red[0][tid];
}

// ---------------- top-2 ----------------
__global__ void topk_kernel(const float* __restrict__ logits, int* __restrict__ cnt,
                            int* __restrict__ tokList, float* __restrict__ wList) {
  const int t = blockIdx.x * blockDim.x + threadIdx.x;
  if (t >= Tc) return;
  float l[Ec];
#pragma unroll
  for (int e = 0; e < Ec; ++e) l[e] = logits[(size_t)t * Ec + e];
  float b0 = -3.4e38f, b1 = -3.4e38f;
  int i0 = 0, i1 = 0;
#pragma unroll
  for (int e = 0; e < Ec; ++e) {
    if (l[e] > b0) { b1 = b0; i1 = i0; b0 = l[e]; i0 = e; }
    else if (l[e] > b1) { b1 = l[e]; i1 = e; }
  }
  const float w0 = 1.f / (1.f + expf(b1 - b0));
  const float w1 = 1.f - w0;
  int p0 = atomicAdd(&cnt[i0], 1);
  tokList[i0 * Tc + p0] = t;
  wList[i0 * Tc + p0] = w0;
  int p1 = atomicAdd(&cnt[i1], 1);
  tokList[i1 * Tc + p1] = t;
  wList[i1 * Tc + p1] = w1;
}

__global__ void offsets_kernel(const int* __restrict__ cnt, int* __restrict__ off) {
  if (threadIdx.x == 0) {
    int s = 0;
    for (int e = 0; e < Ec; ++e) { off[e] = s; s += cnt[e]; }
  }
}

// ---------------- weight convert into STAGED-TILE order ----------------
// fp32 [E][K][N] -> bf16 staged [e][nb=N/64][ks=K/32][q=4][n=64][j=8]; chunk = 4KB.
template <bool SPLIT>
__global__ __launch_bounds__(256) void wconv_kernel(const float* __restrict__ src,
                                                    unsigned short* __restrict__ dh,
                                                    unsigned short* __restrict__ dl,
                                                    int K, int N) {
  const int e = blockIdx.z;
  const int n0 = blockIdx.x * 64;
  const int k0 = blockIdx.y * 64;
  const int NB = N >> 6, KS = K >> 5;
  src += (size_t)e * K * N;

  __shared__ unsigned short lh[64][66];
  __shared__ unsigned short ll[SPLIT ? 64 : 1][66];
  const int tid = threadIdx.x;

  {
    const int r = tid >> 2, cg = (tid & 3) * 16;
    const float* sp = src + (size_t)(k0 + r) * N + n0 + cg;
#pragma unroll
    for (int i = 0; i < 16; i += 4) {
      const float4 v = *(const float4*)(sp + i);
      const float f[4] = {v.x, v.y, v.z, v.w};
#pragma unroll
      for (int j = 0; j < 4; ++j) {
        const unsigned short h = f2bf(f[j]);
        lh[r][cg + i + j] = h;
        if constexpr (SPLIT) ll[r][cg + i + j] = f2bf(f[j] - bf2f(h));
      }
    }
  }
  __syncthreads();
  {
    const int ksl = tid >> 7, q = (tid >> 5) & 3, n2 = (tid & 31) * 2;
    const int kb = ksl * 32 + q * 8;
    union { unsigned short s[16]; uint4 u[2]; } oh, ol;
#pragma unroll
    for (int s = 0; s < 2; ++s)
#pragma unroll
      for (int i = 0; i < 8; ++i) {
        oh.s[s * 8 + i] = lh[kb + i][n2 + s];
        if constexpr (SPLIT) ol.s[s * 8 + i] = ll[kb + i][n2 + s];
      }
    const size_t cb =
        (((size_t)e * NB + (n0 >> 6)) * KS + (k0 >> 5) + ksl) * 2048 + q * 512 + n2 * 8;
    *(uint4*)(dh + cb) = oh.u[0];
    *(uint4*)(dh + cb + 8) = oh.u[1];
    if constexpr (SPLIT) {
      *(uint4*)(dl + cb) = ol.u[0];
      *(uint4*)(dl + cb + 8) = ol.u[1];
    }
  }
}

// ---------------- gate_up GEMM: BM=128, BN=64(g)+64(u), BK=32 ----------------
// B: staged chunks via gl2lds, 3-buffer depth-2 pipeline, counted vmcnt (T3/T4).
// A: reg->LDS [128][40] padded, 2-buffer. One raw s_barrier per step.
template <bool SPLIT>
__global__ __launch_bounds__(256) void gateup_kernel(
    const unsigned short* __restrict__ xh, const unsigned short* __restrict__ xl,
    const unsigned short* __restrict__ gwSh, const unsigned short* __restrict__ gwSl,
    const int* __restrict__ cnt, const int* __restrict__ off,
    const int* __restrict__ tokList, unsigned short* __restrict__ actH,
    unsigned short* __restrict__ actL) {
  // bijective chunked XCD swizzle (grid % 8 == 0): mi fastest, e middle, nb slowest
  const int d = blockIdx.x;
  const int lid = (d & 7) * ((int)gridDim.x >> 3) + (d >> 3);
  const int mi = lid & 15;
  const int e = (lid >> 4) & 7;
  const int nb = lid >> 7;  // 0..31
  const int M = cnt[e];
  const int m0 = mi * 128;
  if (m0 >= M) return;
  const int tid = threadIdx.x;
  const int wv = tid >> 6, l64 = tid & 63;
  const int q = l64 >> 4, mr = l64 & 15;
  const int nc = wv * 16 + mr;
  const int wvo = wv * 1024;

  __shared__ __align__(16) unsigned short sBgh[3][2048];
  __shared__ __align__(16) unsigned short sBgl[3][SPLIT ? 2048 : 8];
  __shared__ __align__(16) unsigned short sBuh[3][2048];
  __shared__ __align__(16) unsigned short sBul[3][SPLIT ? 2048 : 8];
  __shared__ __align__(16) unsigned short sAh[2][128 * 40];
  __shared__ __align__(16) unsigned short sAl[2][SPLIT ? 128 * 40 : 8];

  const size_t gBase = (((size_t)e * 64 + nb) * 32) * 2048 + tid * 8;
  const size_t uBase = (((size_t)e * 64 + nb + 32) * 32) * 2048 + tid * 8;

  const int ar = tid >> 2, ak = (tid & 3) * 8;
  int r0 = m0 + ar;      if (r0 >= M) r0 = M - 1;
  int r1 = m0 + 64 + ar; if (r1 >= M) r1 = M - 1;
  const size_t a0o = (size_t)tokList[e * Tc + r0] * Hc + ak;
  const size_t a1o = (size_t)tokList[e * Tc + r1] * Hc + ak;

  f32x4 accg[8], accu[8];
#pragma unroll
  for (int i = 0; i < 8; ++i) {
    accg[i] = f32x4{0.f, 0.f, 0.f, 0.f};
    accu[i] = f32x4{0.f, 0.f, 0.f, 0.f};
  }

  uint4 pa0h{}, pa1h{}, pa0l{}, pa1l{};
  uint4 pb0h{}, pb1h{}, pb0l{}, pb1l{};

  // ---- prologue: A slice0 -> regs -> LDS[0]; B chunk0 -> buf0; A slice1 regs; B chunk1 -> buf1
  pa0h = *(const uint4*)(xh + a0o);
  pa1h = *(const uint4*)(xh + a1o);
  if constexpr (SPLIT) {
    pa0l = *(const uint4*)(xl + a0o);
    pa1l = *(const uint4*)(xl + a1o);
  }
  gl2lds(gwSh + gBase, (char*)sBgh[0] + wvo);
  gl2lds(gwSh + uBase, (char*)sBuh[0] + wvo);
  if constexpr (SPLIT) {
    gl2lds(gwSl + gBase, (char*)sBgl[0] + wvo);
    gl2lds(gwSl + uBase, (char*)sBul[0] + wvo);
  }
  *(uint4*)&sAh[0][ar * 40 + ak] = pa0h;
  *(uint4*)&sAh[0][(ar + 64) * 40 + ak] = pa1h;
  if constexpr (SPLIT) {
    *(uint4*)&sAl[0][ar * 40 + ak] = pa0l;
    *(uint4*)&sAl[0][(ar + 64) * 40 + ak] = pa1l;
  }
  pa0h = *(const uint4*)(xh + a0o + 32);
  pa1h = *(const uint4*)(xh + a1o + 32);
  if constexpr (SPLIT) {
    pa0l = *(const uint4*)(xl + a0o + 32);
    pa1l = *(const uint4*)(xl + a1o + 32);
  }
  gl2lds(gwSh + gBase + 2048, (char*)sBgh[1] + wvo);
  gl2lds(gwSh + uBase + 2048, (char*)sBuh[1] + wvo);
  if constexpr (SPLIT) {
    gl2lds(gwSl + gBase + 2048, (char*)sBgl[1] + wvo);
    gl2lds(gwSl + uBase + 2048, (char*)sBul[1] + wvo);
  }
  if constexpr (SPLIT)
    asm volatile("s_waitcnt vmcnt(8) lgkmcnt(0)" ::: "memory");
  else
    asm volatile("s_waitcnt vmcnt(4) lgkmcnt(0)" ::: "memory");
  __builtin_amdgcn_s_barrier();
  __builtin_amdgcn_sched_barrier(0);

  int cbuf = 0, ibuf = 2;

#define GU_STEP(T, RB, WB, O0H, O1H, O0L, O1L, N0H, N1H, N0L, N1L)                      \
  {                                                                                     \
    if ((T) + 2 < 32) {                                                                 \
      N0H = *(const uint4*)(xh + a0o + ((T) + 2) * 32);                                 \
      N1H = *(const uint4*)(xh + a1o + ((T) + 2) * 32);                                 \
      if constexpr (SPLIT) {                                                            \
        N0L = *(const uint4*)(xl + a0o + ((T) + 2) * 32);                               \
        N1L = *(const uint4*)(xl + a1o + ((T) + 2) * 32);                               \
      }                                                                                 \
      gl2lds(gwSh + gBase + (size_t)((T) + 2) * 2048, (char*)sBgh[ibuf] + wvo);         \
      gl2lds(gwSh + uBase + (size_t)((T) + 2) * 2048, (char*)sBuh[ibuf] + wvo);         \
      if constexpr (SPLIT) {                                                            \
        gl2lds(gwSl + gBase + (size_t)((T) + 2) * 2048, (char*)sBgl[ibuf] + wvo);       \
        gl2lds(gwSl + uBase + (size_t)((T) + 2) * 2048, (char*)sBul[ibuf] + wvo);       \
      }                                                                                 \
    }                                                                                   \
    if ((T) + 1 < 32) {                                                                 \
      *(uint4*)&sAh[WB][ar * 40 + ak] = O0H;                                            \
      *(uint4*)&sAh[WB][(ar + 64) * 40 + ak] = O1H;                                     \
      if constexpr (SPLIT) {                                                            \
        *(uint4*)&sAl[WB][ar * 40 + ak] = O0L;                                          \
        *(uint4*)&sAl[WB][(ar + 64) * 40 + ak] = O1L;                                   \
      }                                                                                 \
    }                                                                                   \
    const bf16x8 bghf = ldfrag(&sBgh[cbuf][(q * 64 + nc) * 8]);                         \
    const bf16x8 buhf = ldfrag(&sBuh[cbuf][(q * 64 + nc) * 8]);                         \
    bf16x8 bglf, bulf;                                                                  \
    if constexpr (SPLIT) {                                                              \
      bglf = ldfrag(&sBgl[cbuf][(q * 64 + nc) * 8]);                                    \
      bulf = ldfrag(&sBul[cbuf][(q * 64 + nc) * 8]);                                    \
    }                                                                                   \
    _Pragma("unroll")                                                                   \
    for (int mt = 0; mt < 8; ++mt) {                                                    \
      const bf16x8 ah = ldfrag(&sAh[RB][(mt * 16 + mr) * 40 + q * 8]);                  \
      accg[mt] = __builtin_amdgcn_mfma_f32_16x16x32_bf16(ah, bghf, accg[mt], 0, 0, 0);  \
      accu[mt] = __builtin_amdgcn_mfma_f32_16x16x32_bf16(ah, buhf, accu[mt], 0, 0, 0);  \
      if constexpr (SPLIT) {                                                            \
        const bf16x8 alr = ldfrag(&sAl[RB][(mt * 16 + mr) * 40 + q * 8]);               \
        accg[mt] = __builtin_amdgcn_mfma_f32_16x16x32_bf16(ah, bglf, accg[mt], 0, 0, 0);\
        accg[mt] = __builtin_amdgcn_mfma_f32_16x16x32_bf16(alr, bghf, accg[mt], 0, 0, 0);\
        accu[mt] = __builtin_amdgcn_mfma_f32_16x16x32_bf16(ah, bulf, accu[mt], 0, 0, 0);\
        accu[mt] = __builtin_amdgcn_mfma_f32_16x16x32_bf16(alr, buhf, accu[mt], 0, 0, 0);\
      }                                                                                 \
    }                                                                                   \
    if ((T) < 31) {                                                                     \
      if ((T) + 2 < 32) {                                                               \
        if constexpr (SPLIT)                                                            \
          asm volatile("s_waitcnt vmcnt(8) lgkmcnt(0)" ::: "memory");                   \
        else                                                                            \
          asm volatile("s_waitcnt vmcnt(4) lgkmcnt(0)" ::: "memory");                   \
      } else {                                                                          \
        asm volatile("s_waitcnt vmcnt(0) lgkmcnt(0)" ::: "memory");                     \
      }                                                                                 \
      __builtin_amdgcn_s_barrier();                                                     \
      __builtin_amdgcn_sched_barrier(0);                                                \
    }                                                                                   \
    cbuf = cbuf == 2 ? 0 : cbuf + 1;                                                    \
    ibuf = ibuf == 2 ? 0 : ibuf + 1;                                                    \
  }

  for (int t = 0; t < 32; t += 2) {
    GU_STEP(t, 0, 1, pa0h, pa1h, pa0l, pa1l, pb0h, pb1h, pb0l, pb1l)
    GU_STEP(t + 1, 1, 0, pb0h, pb1h, pb0l, pb1l, pa0h, pa1h, pa0l, pa1l)
  }
#undef GU_STEP

  const int valid = M - m0;
  const int rowbase = off[e] + m0;
#pragma unroll
  for (int mt = 0; mt < 8; ++mt) {
#pragma unroll
    for (int r = 0; r < 4; ++r) {
      const int row = mt * 16 + q * 4 + r;  // C/D: row=(lane>>4)*4+reg, col=lane&15 (m89)
      if (row < valid) {
        const float g = accg[mt][r];
        const float u = accu[mt][r];
        const float a = (g / (1.f + expf(-g))) * u;
        const size_t idx = (size_t)(rowbase + row) * Ic + (nb * 64 + nc);
        const unsigned short h = f2bf(a);
        actH[idx] = h;
        if constexpr (SPLIT) actL[idx] = f2bf(a - bf2f(h));
      }
    }
  }
}

// ---------------- down GEMM: BM=128, BN=64, K=Ic, same pipeline ----------------
template <bool SPLIT>
__global__ __launch_bounds__(256) void down_kernel(
    const unsigned short* __restrict__ actH, const unsigned short* __restrict__ actL,
    const unsigned short* __restrict__ dwSh, const unsigned short* __restrict__ dwSl,
    const int* __restrict__ cnt, const int* __restrict__ off,
    const int* __restrict__ tokList, const float* __restrict__ wList,
    float* __restrict__ out) {
  const int d = blockIdx.x;
  const int lid = (d & 7) * ((int)gridDim.x >> 3) + (d >> 3);
  const int mi = lid & 15;
  const int e = (lid >> 4) & 7;
  const int nb = lid >> 7;  // 0..15
  const int M = cnt[e];
  const int m0 = mi * 128;
  if (m0 >= M) return;
  const int tid = threadIdx.x;
  const int wv = tid >> 6, l64 = tid & 63;
  const int q = l64 >> 4, mr = l64 & 15;
  const int nc = wv * 16 + mr;
  const int wvo = wv * 1024;

  __shared__ __align__(16) unsigned short sBh[3][2048];
  __shared__ __align__(16) unsigned short sBl[3][SPLIT ? 2048 : 8];
  __shared__ __align__(16) unsigned short sAh[2][128 * 40];
  __shared__ __align__(16) unsigned short sAl[2][SPLIT ? 128 * 40 : 8];
  __shared__ int sTok[128];
  __shared__ float sW[128];

  if (tid < 128) {
    int r = m0 + tid;
    int rc = r < M ? r : M - 1;
    sTok[tid] = tokList[e * Tc + rc];
    sW[tid] = wList[e * Tc + rc];
  }

  const size_t bBase = (((size_t)e * 16 + nb) * 64) * 2048 + tid * 8;
  const int offE = off[e];

  const int ar = tid >> 2, ak = (tid & 3) * 8;
  int r0 = m0 + ar;      if (r0 >= M) r0 = M - 1;
  int r1 = m0 + 64 + ar; if (r1 >= M) r1 = M - 1;
  const size_t a0o = (size_t)(offE + r0) * Ic + ak;
  const size_t a1o = (size_t)(offE + r1) * Ic + ak;

  f32x4 acc[8];
#pragma unroll
  for (int i = 0; i < 8; ++i) acc[i] = f32x4{0.f, 0.f, 0.f, 0.f};

  uint4 pa0h{}, pa1h{}, pa0l{}, pa1l{};
  uint4 pb0h{}, pb1h{}, pb0l{}, pb1l{};

  pa0h = *(const uint4*)(actH + a0o);
  pa1h = *(const uint4*)(actH + a1o);
  if constexpr (SPLIT) {
    pa0l = *(const uint4*)(actL + a0o);
    pa1l = *(const uint4*)(actL + a1o);
  }
  gl2lds(dwSh + bBase, (char*)sBh[0] + wvo);
  if constexpr (SPLIT) gl2lds(dwSl + bBase, (char*)sBl[0] + wvo);
  *(uint4*)&sAh[0][ar * 40 + ak] = pa0h;
  *(uint4*)&sAh[0][(ar + 64) * 40 + ak] = pa1h;
  if constexpr (SPLIT) {
    *(uint4*)&sAl[0][ar * 40 + ak] = pa0l;
    *(uint4*)&sAl[0][(ar + 64) * 40 + ak] = pa1l;
  }
  pa0h = *(const uint4*)(actH + a0o + 32);
  pa1h = *(const uint4*)(actH + a1o + 32);
  if constexpr (SPLIT) {
    pa0l = *(const uint4*)(actL + a0o + 32);
    pa1l = *(const uint4*)(actL + a1o + 32);
  }
  gl2lds(dwSh + bBase + 2048, (char*)sBh[1] + wvo);
  if constexpr (SPLIT) gl2lds(dwSl + bBase + 2048, (char*)sBl[1] + wvo);
  if constexpr (SPLIT)
    asm volatile("s_waitcnt vmcnt(6) lgkmcnt(0)" ::: "memory");
  else
    asm volatile("s_waitcnt vmcnt(3) lgkmcnt(0)" ::: "memory");
  __builtin_amdgcn_s_barrier();
  __builtin_amdgcn_sched_barrier(0);

  int cbuf = 0, ibuf = 2;

#define DN_STEP(T, RB, WB, O0H, O1H, O0L, O1L, N0H, N1H, N0L, N1L)                      \
  {                                                                                     \
    if ((T) + 2 < 64) {                                                                 \
      N0H = *(const uint4*)(actH + a0o + ((T) + 2) * 32);                               \
      N1H = *(const uint4*)(actH + a1o + ((T) + 2) * 32);                               \
      if constexpr (SPLIT) {                                                            \
        N0L = *(const uint4*)(actL + a0o + ((T) + 2) * 32);                             \
        N1L = *(const uint4*)(actL + a1o + ((T) + 2) * 32);                             \
      }                                                                                 \
      gl2lds(dwSh + bBase + (size_t)((T) + 2) * 2048, (char*)sBh[ibuf] + wvo);          \
      if constexpr (SPLIT)                                                              \
        gl2lds(dwSl + bBase + (size_t)((T) + 2) * 2048, (char*)sBl[ibuf] + wvo);        \
    }                                                                                   \
    if ((T) + 1 < 64) {                                                                 \
      *(uint4*)&sAh[WB][ar * 40 + ak] = O0H;                                            \
      *(uint4*)&sAh[WB][(ar + 64) * 40 + ak] = O1H;                                     \
      if constexpr (SPLIT) {                                                            \
        *(uint4*)&sAl[WB][ar * 40 + ak] = O0L;                                          \
        *(uint4*)&sAl[WB][(ar + 64) * 40 + ak] = O1L;                                   \
      }                                                                                 \
    }                                                                                   \
    const bf16x8 bh = ldfrag(&sBh[cbuf][(q * 64 + nc) * 8]);                            \
    bf16x8 bl;                                                                          \
    if constexpr (SPLIT) bl = ldfrag(&sBl[cbuf][(q * 64 + nc) * 8]);                    \
    _Pragma("unroll")                                                                   \
    for (int mt = 0; mt < 8; ++mt) {                                                    \
      const bf16x8 ah = ldfrag(&sAh[RB][(mt * 16 + mr) * 40 + q * 8]);                  \
      acc[mt] = __builtin_amdgcn_mfma_f32_16x16x32_bf16(ah, bh, acc[mt], 0, 0, 0);      \
      if constexpr (SPLIT) {                                                            \
        const bf16x8 alr = ldfrag(&sAl[RB][(mt * 16 + mr) * 40 + q * 8]);               \
        acc[mt] = __builtin_amdgcn_mfma_f32_16x16x32_bf16(ah, bl, acc[mt], 0, 0, 0);    \
        acc[mt] = __builtin_amdgcn_mfma_f32_16x16x32_bf16(alr, bh, acc[mt], 0, 0, 0);   \
      }                                                                                 \
    }                                                                                   \
    if ((T) < 63) {                                                                     \
      if ((T) + 2 < 64) {                                                               \
        if constexpr (SPLIT)                                                            \
          asm volatile("s_waitcnt vmcnt(6) lgkmcnt(0)" ::: "memory");                   \
        else                                                                            \
          asm volatile("s_waitcnt vmcnt(3) lgkmcnt(0)" ::: "memory");                   \
      } else {                                                                          \
        asm volatile("s_waitcnt vmcnt(0) lgkmcnt(0)" ::: "memory");                     \
      }                                                                                 \
      __builtin_amdgcn_s_barrier();                                                     \
      __builtin_amdgcn_sched_barrier(0);                                                \
    }                                                                                   \
    cbuf = cbuf == 2 ? 0 : cbuf + 1;                                                    \
    ibuf = ibuf == 2 ? 0 : ibuf + 1;                                                    \
  }

  for (int t = 0; t < 64; t += 2) {
    DN_STEP(t, 0, 1, pa0h, pa1h, pa0l, pa1l, pb0h, pb1h, pb0l, pb1l)
    DN_STEP(t + 1, 1, 0, pb0h, pb1h, pb0l, pb1l, pa0h, pa1h, pa0l, pa1l)
  }
#undef DN_STEP

  const int valid = M - m0;
#pragma unroll
  for (int mt = 0; mt < 8; ++mt) {
#pragma unroll
    for (int r = 0; r < 4; ++r) {
      const int row = mt * 16 + q * 4 + r;
      if (row < valid) {
        atomicAdd(&out[(size_t)sTok[row] * Hc + (nb * 64 + nc)], sW[row] * acc[mt][r]);
      }
    }
  }
}

// ---------------- host ----------------
extern "C" void kernel_launch(void* const* d_in, const int* in_sizes, int n_in, void* d_out,
                              int out_size, void* d_ws, size_t ws_size, hipStream_t stream) {
  const float* x_in = (const float*)d_in[0];
  const float* rw = (const float*)d_in[1];
  const float* guw = (const float*)d_in[2];
  const float* dnw = (const float*)d_in[3];
  float* out = (float*)d_out;
  float* logits_base = out + (size_t)Tc * Hc;

  uint8_t* w = (uint8_t*)d_ws;
  float* x1 = (float*)w;                    w += (size_t)Tc * Hc * 4;
  unsigned short* xh = (unsigned short*)w;  w += (size_t)Tc * Hc * 2;
  unsigned short* xl = (unsigned short*)w;  w += (size_t)Tc * Hc * 2;
  unsigned short* actH = (unsigned short*)w; w += (size_t)Tc * 2 * Ic * 2;
  unsigned short* actL = (unsigned short*)w; w += (size_t)Tc * 2 * Ic * 2;
  int* tokList = (int*)w;                   w += (size_t)Ec * Tc * 4;
  float* wList = (float*)w;                 w += (size_t)Ec * Tc * 4;
  int* cnt0 = (int*)w;                      w += 64;
  int* cnt1 = (int*)w;                      w += 64;
  int* off = (int*)w;                       w += 64;
  unsigned short* wTh = (unsigned short*)w; w += (size_t)Ec * 2 * Ic * Hc * 2;
  unsigned short* wTl = (unsigned short*)w; w += (size_t)Ec * 2 * Ic * Hc * 2;

  hipMemsetAsync(cnt0, 0, 192, stream);
  hipMemsetAsync(x1, 0, (size_t)Tc * Hc * 4, stream);
  hipMemsetAsync(out, 0, (size_t)Tc * Hc * 4, stream);

  // ---- layer 0 (split-bf16 precision) ----
  router_kernel<<<Tc, 256, 0, stream>>>(x_in, rw, logits_base, xh, xl);
  topk_kernel<<<Tc / 256, 256, 0, stream>>>(logits_base, cnt0, tokList, wList);
  offsets_kernel<<<1, 64, 0, stream>>>(cnt0, off);
  wconv_kernel<true><<<dim3(2 * Ic / 64, Hc / 64, Ec), 256, 0, stream>>>(guw, wTh, wTl, Hc, 2 * Ic);
  gateup_kernel<true><<<16 * 32 * Ec, 256, 0, stream>>>(xh, xl, wTh, wTl, cnt0, off,
                                                        tokList, actH, actL);
  wconv_kernel<true><<<dim3(Hc / 64, Ic / 64, Ec), 256, 0, stream>>>(dnw, wTh, wTl, Ic, Hc);
  down_kernel<true><<<16 * 16 * Ec, 256, 0, stream>>>(actH, actL, wTh, wTl, cnt0,
                                                      off, tokList, wList, x1);

  // ---- layer 1 (plain bf16) ----
  const float* rw1 = rw + (size_t)Hc * Ec;
  const float* guw1 = guw + (size_t)Ec * Hc * 2 * Ic;
  const float* dnw1 = dnw + (size_t)Ec * Ic * Hc;
  router_kernel<<<Tc, 256, 0, stream>>>(x1, rw1, logits_base + (size_t)Tc * Ec, xh, xl);
  topk_kernel<<<Tc / 256, 256, 0, stream>>>(logits_base + (size_t)Tc * Ec, cnt1, tokList, wList);
  offsets_kernel<<<1, 64, 0, stream>>>(cnt1, off);
  wconv_kernel<false><<<dim3(2 * Ic / 64, Hc / 64, Ec), 256, 0, stream>>>(guw1, wTh, wTl, Hc, 2 * Ic);
  gateup_kernel<false><<<16 * 32 * Ec, 256, 0, stream>>>(xh, xl, wTh, wTl, cnt1, off,
                                                         tokList, actH, actL);
  wconv_kernel<false><<<dim3(Hc / 64, Ic / 64, Ec), 256, 0, stream>>>(dnw1, wTh, wTl, Ic, Hc);
  down_kernel<false><<<16 * 16 * Ec, 256, 0, stream>>>(actH, actL, wTh, wTl, cnt1,
                                                       off, tokList, wList, out);
}

// Round 7
// 935.154 us; speedup vs baseline: 1.9096x; 1.1403x over previous
//
#include <hip/hip_runtime.h>
#include <cstdint>
#include <cstddef>

constexpr int Lc = 2, Ec = 8, Hc = 1024, Ic = 2048, Tc = 2048;

typedef __bf16 bf16x8 __attribute__((ext_vector_type(8)));
typedef float f32x4 __attribute__((ext_vector_type(4)));

__device__ __forceinline__ unsigned short f2bf(float f) {
  unsigned u = __builtin_bit_cast(unsigned, f);
  u = (u + 0x7fffu + ((u >> 16) & 1u)) >> 16;
  return (unsigned short)u;
}
__device__ __forceinline__ float bf2f(unsigned short h) {
  unsigned u = (unsigned)h << 16;
  return __builtin_bit_cast(float, u);
}
__device__ __forceinline__ bf16x8 ldfrag(const unsigned short* p) {
  return __builtin_bit_cast(bf16x8, *(const uint4*)p);
}

// ---------------- router + fp32->(hi,lo) bf16 convert (fused) ----------------
__global__ __launch_bounds__(256) void router_kernel(
    const float* __restrict__ x, const float* __restrict__ rw, float* __restrict__ logits,
    unsigned short* __restrict__ xh, unsigned short* __restrict__ xl) {
  const int t = blockIdx.x;
  const int tid = threadIdx.x;
  const float* xr = x + (size_t)t * Hc;
  const int h0 = tid * 4;
  const float4 v = *(const float4*)(xr + h0);
  const float f[4] = {v.x, v.y, v.z, v.w};
  unsigned short hs[4], ls[4];
#pragma unroll
  for (int j = 0; j < 4; ++j) {
    hs[j] = f2bf(f[j]);
    ls[j] = f2bf(f[j] - bf2f(hs[j]));
  }
  *(uint2*)(xh + (size_t)t * Hc + h0) =
      uint2{(unsigned)hs[0] | ((unsigned)hs[1] << 16), (unsigned)hs[2] | ((unsigned)hs[3] << 16)};
  *(uint2*)(xl + (size_t)t * Hc + h0) =
      uint2{(unsigned)ls[0] | ((unsigned)ls[1] << 16), (unsigned)ls[2] | ((unsigned)ls[3] << 16)};

  float acc[Ec];
#pragma unroll
  for (int e = 0; e < Ec; ++e) acc[e] = 0.f;
#pragma unroll
  for (int j = 0; j < 4; ++j) {
    const float* w = rw + (size_t)(h0 + j) * Ec;
#pragma unroll
    for (int e = 0; e < Ec; ++e) acc[e] += f[j] * w[e];
  }
  __shared__ float red[256][Ec];
#pragma unroll
  for (int e = 0; e < Ec; ++e) red[tid][e] = acc[e];
  __syncthreads();
  for (int s = 128; s > 0; s >>= 1) {
    if (tid < s) {
#pragma unroll
      for (int e = 0; e < Ec; ++e) red[tid][e] += red[tid + s][e];
    }
    __syncthreads();
  }
  if (tid < Ec) logits[(size_t)t * Ec + tid] = red[0][tid];
}

// ---------------- top-2 ----------------
__global__ void topk_kernel(const float* __restrict__ logits, int* __restrict__ cnt,
                            int* __restrict__ tokList, float* __restrict__ wList) {
  const int t = blockIdx.x * blockDim.x + threadIdx.x;
  if (t >= Tc) return;
  float l[Ec];
#pragma unroll
  for (int e = 0; e < Ec; ++e) l[e] = logits[(size_t)t * Ec + e];
  float b0 = -3.4e38f, b1 = -3.4e38f;
  int i0 = 0, i1 = 0;
#pragma unroll
  for (int e = 0; e < Ec; ++e) {
    if (l[e] > b0) { b1 = b0; i1 = i0; b0 = l[e]; i0 = e; }
    else if (l[e] > b1) { b1 = l[e]; i1 = e; }
  }
  const float w0 = 1.f / (1.f + expf(b1 - b0));
  const float w1 = 1.f - w0;
  int p0 = atomicAdd(&cnt[i0], 1);
  tokList[i0 * Tc + p0] = t;
  wList[i0 * Tc + p0] = w0;
  int p1 = atomicAdd(&cnt[i1], 1);
  tokList[i1 * Tc + p1] = t;
  wList[i1 * Tc + p1] = w1;
}

__global__ void offsets_kernel(const int* __restrict__ cnt, int* __restrict__ off) {
  if (threadIdx.x == 0) {
    int s = 0;
    for (int e = 0; e < Ec; ++e) { off[e] = s; s += cnt[e]; }
  }
}

// ---------------- weight convert into STAGED-TILE order ----------------
// fp32 [E][K][N] -> bf16 staged [e][nb=N/64][ks=K/32][q=4][n=64][j=8]; chunk = 4KB.
template <bool SPLIT>
__global__ __launch_bounds__(256) void wconv_kernel(const float* __restrict__ src,
                                                    unsigned short* __restrict__ dh,
                                                    unsigned short* __restrict__ dl,
                                                    int K, int N) {
  const int e = blockIdx.z;
  const int n0 = blockIdx.x * 64;
  const int k0 = blockIdx.y * 64;
  const int NB = N >> 6, KS = K >> 5;
  src += (size_t)e * K * N;

  __shared__ unsigned short lh[64][66];
  __shared__ unsigned short ll[SPLIT ? 64 : 1][66];
  const int tid = threadIdx.x;

  {
    const int r = tid >> 2, cg = (tid & 3) * 16;
    const float* sp = src + (size_t)(k0 + r) * N + n0 + cg;
#pragma unroll
    for (int i = 0; i < 16; i += 4) {
      const float4 v = *(const float4*)(sp + i);
      const float f[4] = {v.x, v.y, v.z, v.w};
#pragma unroll
      for (int j = 0; j < 4; ++j) {
        const unsigned short h = f2bf(f[j]);
        lh[r][cg + i + j] = h;
        if constexpr (SPLIT) ll[r][cg + i + j] = f2bf(f[j] - bf2f(h));
      }
    }
  }
  __syncthreads();
  {
    const int ksl = tid >> 7, q = (tid >> 5) & 3, n2 = (tid & 31) * 2;
    const int kb = ksl * 32 + q * 8;
    union { unsigned short s[16]; uint4 u[2]; } oh, ol;
#pragma unroll
    for (int s = 0; s < 2; ++s)
#pragma unroll
      for (int i = 0; i < 8; ++i) {
        oh.s[s * 8 + i] = lh[kb + i][n2 + s];
        if constexpr (SPLIT) ol.s[s * 8 + i] = ll[kb + i][n2 + s];
      }
    const size_t cb =
        (((size_t)e * NB + (n0 >> 6)) * KS + (k0 >> 5) + ksl) * 2048 + q * 512 + n2 * 8;
    *(uint4*)(dh + cb) = oh.u[0];
    *(uint4*)(dh + cb + 8) = oh.u[1];
    if constexpr (SPLIT) {
      *(uint4*)(dl + cb) = ol.u[0];
      *(uint4*)(dl + cb + 8) = ol.u[1];
    }
  }
}

// ---------------- gate_up GEMM: BM=128, BN=64(g)+64(u), BK=32 ----------------
// B fragments: DIRECT global->VGPR from staged layout (per-lane contiguous 16B),
// double-buffered in registers -- no LDS, no barrier coupling.
// A: reg->LDS [128][40] padded, 2-buffer; raw s_barrier fences only lgkm (A writes).
template <bool SPLIT>
__global__ __launch_bounds__(256, SPLIT ? 3 : 4) void gateup_kernel(
    const unsigned short* __restrict__ xh, const unsigned short* __restrict__ xl,
    const unsigned short* __restrict__ gwSh, const unsigned short* __restrict__ gwSl,
    const int* __restrict__ cnt, const int* __restrict__ off,
    const int* __restrict__ tokList, unsigned short* __restrict__ actH,
    unsigned short* __restrict__ actL) {
  // bijective chunked XCD swizzle (grid % 8 == 0): mi fastest, e middle, nb slowest
  const int d = blockIdx.x;
  const int lid = (d & 7) * ((int)gridDim.x >> 3) + (d >> 3);
  const int mi = lid & 15;
  const int e = (lid >> 4) & 7;
  const int nb = lid >> 7;  // 0..31
  const int M = cnt[e];
  const int m0 = mi * 128;
  if (m0 >= M) return;
  const int tid = threadIdx.x;
  const int wv = tid >> 6, l64 = tid & 63;
  const int q = l64 >> 4, mr = l64 & 15;
  const int nc = wv * 16 + mr;

  __shared__ __align__(16) unsigned short sAh[2][128 * 40];
  __shared__ __align__(16) unsigned short sAl[2][SPLIT ? 128 * 40 : 8];

  // staged-weight fragment bases (element units): chunk(e,nb,ks) + (q*64+nc)*8
  const size_t fragoff = (size_t)(q * 64 + nc) * 8;
  const size_t gBase = (((size_t)e * 64 + nb) * 32) * 2048 + fragoff;
  const size_t uBase = (((size_t)e * 64 + nb + 32) * 32) * 2048 + fragoff;

  const int ar = tid >> 2, ak = (tid & 3) * 8;
  int r0 = m0 + ar;      if (r0 >= M) r0 = M - 1;
  int r1 = m0 + 64 + ar; if (r1 >= M) r1 = M - 1;
  const size_t a0o = (size_t)tokList[e * Tc + r0] * Hc + ak;
  const size_t a1o = (size_t)tokList[e * Tc + r1] * Hc + ak;

  f32x4 accg[8], accu[8];
#pragma unroll
  for (int i = 0; i < 8; ++i) {
    accg[i] = f32x4{0.f, 0.f, 0.f, 0.f};
    accu[i] = f32x4{0.f, 0.f, 0.f, 0.f};
  }

  uint4 paA0h{}, paA1h{}, paA0l{}, paA1l{};
  uint4 paB0h{}, paB1h{}, paB0l{}, paB1l{};
  bf16x8 bcAgh{}, bcAuh{}, bcAgl{}, bcAul{};
  bf16x8 bcBgh{}, bcBuh{}, bcBgl{}, bcBul{};

  // ---- prologue: A(0) -> LDS[0]; B(0) -> regs(A); A(1) -> regs(A)
  paA0h = *(const uint4*)(xh + a0o);
  paA1h = *(const uint4*)(xh + a1o);
  if constexpr (SPLIT) {
    paA0l = *(const uint4*)(xl + a0o);
    paA1l = *(const uint4*)(xl + a1o);
  }
  *(uint4*)&sAh[0][ar * 40 + ak] = paA0h;
  *(uint4*)&sAh[0][(ar + 64) * 40 + ak] = paA1h;
  if constexpr (SPLIT) {
    *(uint4*)&sAl[0][ar * 40 + ak] = paA0l;
    *(uint4*)&sAl[0][(ar + 64) * 40 + ak] = paA1l;
  }
  bcAgh = ldfrag(gwSh + gBase);
  bcAuh = ldfrag(gwSh + uBase);
  if constexpr (SPLIT) {
    bcAgl = ldfrag(gwSl + gBase);
    bcAul = ldfrag(gwSl + uBase);
  }
  paA0h = *(const uint4*)(xh + a0o + 32);
  paA1h = *(const uint4*)(xh + a1o + 32);
  if constexpr (SPLIT) {
    paA0l = *(const uint4*)(xl + a0o + 32);
    paA1l = *(const uint4*)(xl + a1o + 32);
  }
  asm volatile("s_waitcnt lgkmcnt(0)" ::: "memory");
  __builtin_amdgcn_s_barrier();

// step T: compute LDS[CUR] x BC; load B(T+1)->BN regs, A(T+2)->PN regs;
// ds_write PA (=A(T+1)) -> LDS[NX]; lgkm-only barrier.
#define GU_STEP(T, CUR, NX, PA0H, PA1H, PA0L, PA1L, PN0H, PN1H, PN0L, PN1L,             \
                BCGH, BCUH, BCGL, BCUL, BNGH, BNUH, BNGL, BNUL)                         \
  {                                                                                     \
    if ((T) + 1 < 32) {                                                                 \
      BNGH = ldfrag(gwSh + gBase + (size_t)((T) + 1) * 2048);                           \
      BNUH = ldfrag(gwSh + uBase + (size_t)((T) + 1) * 2048);                           \
      if constexpr (SPLIT) {                                                            \
        BNGL = ldfrag(gwSl + gBase + (size_t)((T) + 1) * 2048);                         \
        BNUL = ldfrag(gwSl + uBase + (size_t)((T) + 1) * 2048);                         \
      }                                                                                 \
    }                                                                                   \
    if ((T) + 2 < 32) {                                                                 \
      PN0H = *(const uint4*)(xh + a0o + ((T) + 2) * 32);                                \
      PN1H = *(const uint4*)(xh + a1o + ((T) + 2) * 32);                                \
      if constexpr (SPLIT) {                                                            \
        PN0L = *(const uint4*)(xl + a0o + ((T) + 2) * 32);                              \
        PN1L = *(const uint4*)(xl + a1o + ((T) + 2) * 32);                              \
      }                                                                                 \
    }                                                                                   \
    if ((T) + 1 < 32) {                                                                 \
      *(uint4*)&sAh[NX][ar * 40 + ak] = PA0H;                                           \
      *(uint4*)&sAh[NX][(ar + 64) * 40 + ak] = PA1H;                                    \
      if constexpr (SPLIT) {                                                            \
        *(uint4*)&sAl[NX][ar * 40 + ak] = PA0L;                                         \
        *(uint4*)&sAl[NX][(ar + 64) * 40 + ak] = PA1L;                                  \
      }                                                                                 \
    }                                                                                   \
    __builtin_amdgcn_s_setprio(1);                                                      \
    _Pragma("unroll")                                                                   \
    for (int mt = 0; mt < 8; ++mt) {                                                    \
      const bf16x8 ah = ldfrag(&sAh[CUR][(mt * 16 + mr) * 40 + q * 8]);                 \
      accg[mt] = __builtin_amdgcn_mfma_f32_16x16x32_bf16(ah, BCGH, accg[mt], 0, 0, 0);  \
      accu[mt] = __builtin_amdgcn_mfma_f32_16x16x32_bf16(ah, BCUH, accu[mt], 0, 0, 0);  \
      if constexpr (SPLIT) {                                                            \
        const bf16x8 alr = ldfrag(&sAl[CUR][(mt * 16 + mr) * 40 + q * 8]);              \
        accg[mt] = __builtin_amdgcn_mfma_f32_16x16x32_bf16(ah, BCGL, accg[mt], 0, 0, 0);\
        accg[mt] = __builtin_amdgcn_mfma_f32_16x16x32_bf16(alr, BCGH, accg[mt], 0, 0, 0);\
        accu[mt] = __builtin_amdgcn_mfma_f32_16x16x32_bf16(ah, BCUL, accu[mt], 0, 0, 0);\
        accu[mt] = __builtin_amdgcn_mfma_f32_16x16x32_bf16(alr, BCUH, accu[mt], 0, 0, 0);\
      }                                                                                 \
    }                                                                                   \
    __builtin_amdgcn_s_setprio(0);                                                      \
    if ((T) < 31) {                                                                     \
      asm volatile("s_waitcnt lgkmcnt(0)" ::: "memory");                                \
      __builtin_amdgcn_s_barrier();                                                     \
    }                                                                                   \
  }

  for (int t = 0; t < 32; t += 2) {
    GU_STEP(t, 0, 1, paA0h, paA1h, paA0l, paA1l, paB0h, paB1h, paB0l, paB1l,
            bcAgh, bcAuh, bcAgl, bcAul, bcBgh, bcBuh, bcBgl, bcBul)
    GU_STEP(t + 1, 1, 0, paB0h, paB1h, paB0l, paB1l, paA0h, paA1h, paA0l, paA1l,
            bcBgh, bcBuh, bcBgl, bcBul, bcAgh, bcAuh, bcAgl, bcAul)
  }
#undef GU_STEP

  const int valid = M - m0;
  const int rowbase = off[e] + m0;
#pragma unroll
  for (int mt = 0; mt < 8; ++mt) {
#pragma unroll
    for (int r = 0; r < 4; ++r) {
      const int row = mt * 16 + q * 4 + r;  // C/D: row=(lane>>4)*4+reg, col=lane&15 (m89)
      if (row < valid) {
        const float g = accg[mt][r];
        const float u = accu[mt][r];
        const float a = (g / (1.f + expf(-g))) * u;
        const size_t idx = (size_t)(rowbase + row) * Ic + (nb * 64 + nc);
        const unsigned short h = f2bf(a);
        actH[idx] = h;
        if constexpr (SPLIT) actL[idx] = f2bf(a - bf2f(h));
      }
    }
  }
}

// ---------------- down GEMM: BM=128, BN=64, K=Ic, same structure ----------------
template <bool SPLIT>
__global__ __launch_bounds__(256, 4) void down_kernel(
    const unsigned short* __restrict__ actH, const unsigned short* __restrict__ actL,
    const unsigned short* __restrict__ dwSh, const unsigned short* __restrict__ dwSl,
    const int* __restrict__ cnt, const int* __restrict__ off,
    const int* __restrict__ tokList, const float* __restrict__ wList,
    float* __restrict__ out) {
  const int d = blockIdx.x;
  const int lid = (d & 7) * ((int)gridDim.x >> 3) + (d >> 3);
  const int mi = lid & 15;
  const int e = (lid >> 4) & 7;
  const int nb = lid >> 7;  // 0..15
  const int M = cnt[e];
  const int m0 = mi * 128;
  if (m0 >= M) return;
  const int tid = threadIdx.x;
  const int wv = tid >> 6, l64 = tid & 63;
  const int q = l64 >> 4, mr = l64 & 15;
  const int nc = wv * 16 + mr;

  __shared__ __align__(16) unsigned short sAh[2][128 * 40];
  __shared__ __align__(16) unsigned short sAl[2][SPLIT ? 128 * 40 : 8];
  __shared__ int sTok[128];
  __shared__ float sW[128];

  if (tid < 128) {
    int r = m0 + tid;
    int rc = r < M ? r : M - 1;
    sTok[tid] = tokList[e * Tc + rc];
    sW[tid] = wList[e * Tc + rc];
  }

  const size_t fragoff = (size_t)(q * 64 + nc) * 8;
  const size_t bBase = (((size_t)e * 16 + nb) * 64) * 2048 + fragoff;
  const int offE = off[e];

  const int ar = tid >> 2, ak = (tid & 3) * 8;
  int r0 = m0 + ar;      if (r0 >= M) r0 = M - 1;
  int r1 = m0 + 64 + ar; if (r1 >= M) r1 = M - 1;
  const size_t a0o = (size_t)(offE + r0) * Ic + ak;
  const size_t a1o = (size_t)(offE + r1) * Ic + ak;

  f32x4 acc[8];
#pragma unroll
  for (int i = 0; i < 8; ++i) acc[i] = f32x4{0.f, 0.f, 0.f, 0.f};

  uint4 paA0h{}, paA1h{}, paA0l{}, paA1l{};
  uint4 paB0h{}, paB1h{}, paB0l{}, paB1l{};
  bf16x8 bcAh{}, bcAl{}, bcBh{}, bcBl{};

  paA0h = *(const uint4*)(actH + a0o);
  paA1h = *(const uint4*)(actH + a1o);
  if constexpr (SPLIT) {
    paA0l = *(const uint4*)(actL + a0o);
    paA1l = *(const uint4*)(actL + a1o);
  }
  *(uint4*)&sAh[0][ar * 40 + ak] = paA0h;
  *(uint4*)&sAh[0][(ar + 64) * 40 + ak] = paA1h;
  if constexpr (SPLIT) {
    *(uint4*)&sAl[0][ar * 40 + ak] = paA0l;
    *(uint4*)&sAl[0][(ar + 64) * 40 + ak] = paA1l;
  }
  bcAh = ldfrag(dwSh + bBase);
  if constexpr (SPLIT) bcAl = ldfrag(dwSl + bBase);
  paA0h = *(const uint4*)(actH + a0o + 32);
  paA1h = *(const uint4*)(actH + a1o + 32);
  if constexpr (SPLIT) {
    paA0l = *(const uint4*)(actL + a0o + 32);
    paA1l = *(const uint4*)(actL + a1o + 32);
  }
  asm volatile("s_waitcnt lgkmcnt(0)" ::: "memory");
  __builtin_amdgcn_s_barrier();

#define DN_STEP(T, CUR, NX, PA0H, PA1H, PA0L, PA1L, PN0H, PN1H, PN0L, PN1L,             \
                BCH, BCL, BNH, BNL)                                                     \
  {                                                                                     \
    if ((T) + 1 < 64) {                                                                 \
      BNH = ldfrag(dwSh + bBase + (size_t)((T) + 1) * 2048);                            \
      if constexpr (SPLIT) BNL = ldfrag(dwSl + bBase + (size_t)((T) + 1) * 2048);       \
    }                                                                                   \
    if ((T) + 2 < 64) {                                                                 \
      PN0H = *(const uint4*)(actH + a0o + ((T) + 2) * 32);                              \
      PN1H = *(const uint4*)(actH + a1o + ((T) + 2) * 32);                              \
      if constexpr (SPLIT) {                                                            \
        PN0L = *(const uint4*)(actL + a0o + ((T) + 2) * 32);                            \
        PN1L = *(const uint4*)(actL + a1o + ((T) + 2) * 32);                            \
      }                                                                                 \
    }                                                                                   \
    if ((T) + 1 < 64) {                                                                 \
      *(uint4*)&sAh[NX][ar * 40 + ak] = PA0H;                                           \
      *(uint4*)&sAh[NX][(ar + 64) * 40 + ak] = PA1H;                                    \
      if constexpr (SPLIT) {                                                            \
        *(uint4*)&sAl[NX][ar * 40 + ak] = PA0L;                                         \
        *(uint4*)&sAl[NX][(ar + 64) * 40 + ak] = PA1L;                                  \
      }                                                                                 \
    }                                                                                   \
    __builtin_amdgcn_s_setprio(1);                                                      \
    _Pragma("unroll")                                                                   \
    for (int mt = 0; mt < 8; ++mt) {                                                    \
      const bf16x8 ah = ldfrag(&sAh[CUR][(mt * 16 + mr) * 40 + q * 8]);                 \
      acc[mt] = __builtin_amdgcn_mfma_f32_16x16x32_bf16(ah, BCH, acc[mt], 0, 0, 0);     \
      if constexpr (SPLIT) {                                                            \
        const bf16x8 alr = ldfrag(&sAl[CUR][(mt * 16 + mr) * 40 + q * 8]);              \
        acc[mt] = __builtin_amdgcn_mfma_f32_16x16x32_bf16(ah, BCL, acc[mt], 0, 0, 0);   \
        acc[mt] = __builtin_amdgcn_mfma_f32_16x16x32_bf16(alr, BCH, acc[mt], 0, 0, 0);  \
      }                                                                                 \
    }                                                                                   \
    __builtin_amdgcn_s_setprio(0);                                                      \
    if ((T) < 63) {                                                                     \
      asm volatile("s_waitcnt lgkmcnt(0)" ::: "memory");                                \
      __builtin_amdgcn_s_barrier();                                                     \
    }                                                                                   \
  }

  for (int t = 0; t < 64; t += 2) {
    DN_STEP(t, 0, 1, paA0h, paA1h, paA0l, paA1l, paB0h, paB1h, paB0l, paB1l,
            bcAh, bcAl, bcBh, bcBl)
    DN_STEP(t + 1, 1, 0, paB0h, paB1h, paB0l, paB1l, paA0h, paA1h, paA0l, paA1l,
            bcBh, bcBl, bcAh, bcAl)
  }
#undef DN_STEP

  const int valid = M - m0;
#pragma unroll
  for (int mt = 0; mt < 8; ++mt) {
#pragma unroll
    for (int r = 0; r < 4; ++r) {
      const int row = mt * 16 + q * 4 + r;
      if (row < valid) {
        atomicAdd(&out[(size_t)sTok[row] * Hc + (nb * 64 + nc)], sW[row] * acc[mt][r]);
      }
    }
  }
}

// ---------------- host ----------------
extern "C" void kernel_launch(void* const* d_in, const int* in_sizes, int n_in, void* d_out,
                              int out_size, void* d_ws, size_t ws_size, hipStream_t stream) {
  const float* x_in = (const float*)d_in[0];
  const float* rw = (const float*)d_in[1];
  const float* guw = (const float*)d_in[2];
  const float* dnw = (const float*)d_in[3];
  float* out = (float*)d_out;
  float* logits_base = out + (size_t)Tc * Hc;

  uint8_t* w = (uint8_t*)d_ws;
  float* x1 = (float*)w;                    w += (size_t)Tc * Hc * 4;
  unsigned short* xh = (unsigned short*)w;  w += (size_t)Tc * Hc * 2;
  unsigned short* xl = (unsigned short*)w;  w += (size_t)Tc * Hc * 2;
  unsigned short* actH = (unsigned short*)w; w += (size_t)Tc * 2 * Ic * 2;
  unsigned short* actL = (unsigned short*)w; w += (size_t)Tc * 2 * Ic * 2;
  int* tokList = (int*)w;                   w += (size_t)Ec * Tc * 4;
  float* wList = (float*)w;                 w += (size_t)Ec * Tc * 4;
  int* cnt0 = (int*)w;                      w += 64;
  int* cnt1 = (int*)w;                      w += 64;
  int* off = (int*)w;                       w += 64;
  unsigned short* wTh = (unsigned short*)w; w += (size_t)Ec * 2 * Ic * Hc * 2;
  unsigned short* wTl = (unsigned short*)w; w += (size_t)Ec * 2 * Ic * Hc * 2;

  hipMemsetAsync(cnt0, 0, 192, stream);
  hipMemsetAsync(x1, 0, (size_t)Tc * Hc * 4, stream);
  hipMemsetAsync(out, 0, (size_t)Tc * Hc * 4, stream);

  // ---- layer 0 (split-bf16 precision) ----
  router_kernel<<<Tc, 256, 0, stream>>>(x_in, rw, logits_base, xh, xl);
  topk_kernel<<<Tc / 256, 256, 0, stream>>>(logits_base, cnt0, tokList, wList);
  offsets_kernel<<<1, 64, 0, stream>>>(cnt0, off);
  wconv_kernel<true><<<dim3(2 * Ic / 64, Hc / 64, Ec), 256, 0, stream>>>(guw, wTh, wTl, Hc, 2 * Ic);
  gateup_kernel<true><<<16 * 32 * Ec, 256, 0, stream>>>(xh, xl, wTh, wTl, cnt0, off,
                                                        tokList, actH, actL);
  wconv_kernel<true><<<dim3(Hc / 64, Ic / 64, Ec), 256, 0, stream>>>(dnw, wTh, wTl, Ic, Hc);
  down_kernel<true><<<16 * 16 * Ec, 256, 0, stream>>>(actH, actL, wTh, wTl, cnt0,
                                                      off, tokList, wList, x1);

  // ---- layer 1 (plain bf16) ----
  const float* rw1 = rw + (size_t)Hc * Ec;
  const float* guw1 = guw + (size_t)Ec * Hc * 2 * Ic;
  const float* dnw1 = dnw + (size_t)Ec * Ic * Hc;
  router_kernel<<<Tc, 256, 0, stream>>>(x1, rw1, logits_base + (size_t)Tc * Ec, xh, xl);
  topk_kernel<<<Tc / 256, 256, 0, stream>>>(logits_base + (size_t)Tc * Ec, cnt1, tokList, wList);
  offsets_kernel<<<1, 64, 0, stream>>>(cnt1, off);
  wconv_kernel<false><<<dim3(2 * Ic / 64, Hc / 64, Ec), 256, 0, stream>>>(guw1, wTh, wTl, Hc, 2 * Ic);
  gateup_kernel<false><<<16 * 32 * Ec, 256, 0, stream>>>(xh, xl, wTh, wTl, cnt1, off,
                                                         tokList, actH, actL);
  wconv_kernel<false><<<dim3(Hc / 64, Ic / 64, Ec), 256, 0, stream>>>(dnw1, wTh, wTl, Ic, Hc);
  down_kernel<false><<<16 * 16 * Ec, 256, 0, stream>>>(actH, actL, wTh, wTl, cnt1,
                                                       off, tokList, wList, out);
}

// Round 8
// 887.717 us; speedup vs baseline: 2.0116x; 1.0534x over previous
//
#include <hip/hip_runtime.h>
#include <cstdint>
#include <cstddef>

constexpr int Lc = 2, Ec = 8, Hc = 1024, Ic = 2048, Tc = 2048;

typedef __bf16 bf16x8 __attribute__((ext_vector_type(8)));
typedef float f32x4 __attribute__((ext_vector_type(4)));

__device__ __forceinline__ unsigned short f2bf(float f) {
  unsigned u = __builtin_bit_cast(unsigned, f);
  u = (u + 0x7fffu + ((u >> 16) & 1u)) >> 16;
  return (unsigned short)u;
}
__device__ __forceinline__ float bf2f(unsigned short h) {
  unsigned u = (unsigned)h << 16;
  return __builtin_bit_cast(float, u);
}
__device__ __forceinline__ bf16x8 ldfrag(const unsigned short* p) {
  return __builtin_bit_cast(bf16x8, *(const uint4*)p);
}

// ---------------- weight convert block (device fn, runs as trailing blocks of host launches)
// fp32 [E][K][N] -> bf16 staged [e][nb=N/64][ks=K/32][q=4][n=64][j=8]; chunk = 4KB.
// smem: needs 64*66*2 bytes (hi) + same again for lo when WSPLIT.
template <bool WSPLIT>
__device__ __forceinline__ void wconv_block(const float* __restrict__ src,
                                            unsigned short* __restrict__ dh,
                                            unsigned short* __restrict__ dl,
                                            int K, int N, int idx, char* smem) {
  const int nN = N >> 6, nK = K >> 6;
  const int sN = 31 - __builtin_clz((unsigned)nN);
  const int sK = 31 - __builtin_clz((unsigned)nK);
  const int bx = idx & (nN - 1);
  const int by = (idx >> sN) & (nK - 1);
  const int e = idx >> (sN + sK);
  const int n0 = bx * 64, k0 = by * 64;
  const int NB = N >> 6, KS = K >> 5;
  src += (size_t)e * K * N;

  unsigned short(*lh)[66] = (unsigned short(*)[66])smem;
  unsigned short(*ll)[66] = (unsigned short(*)[66])(smem + 64 * 66 * 2);
  const int tid = threadIdx.x;

  {
    const int r = tid >> 2, cg = (tid & 3) * 16;
    const float* sp = src + (size_t)(k0 + r) * N + n0 + cg;
#pragma unroll
    for (int i = 0; i < 16; i += 4) {
      const float4 v = *(const float4*)(sp + i);
      const float f[4] = {v.x, v.y, v.z, v.w};
#pragma unroll
      for (int j = 0; j < 4; ++j) {
        const unsigned short h = f2bf(f[j]);
        lh[r][cg + i + j] = h;
        if constexpr (WSPLIT) ll[r][cg + i + j] = f2bf(f[j] - bf2f(h));
      }
    }
  }
  __syncthreads();
  {
    const int ksl = tid >> 7, q = (tid >> 5) & 3, n2 = (tid & 31) * 2;
    const int kb = ksl * 32 + q * 8;
    union { unsigned short s[16]; uint4 u[2]; } oh, ol;
#pragma unroll
    for (int s = 0; s < 2; ++s)
#pragma unroll
      for (int i = 0; i < 8; ++i) {
        oh.s[s * 8 + i] = lh[kb + i][n2 + s];
        if constexpr (WSPLIT) ol.s[s * 8 + i] = ll[kb + i][n2 + s];
      }
    const size_t cb =
        (((size_t)e * NB + (n0 >> 6)) * KS + (k0 >> 5) + ksl) * 2048 + q * 512 + n2 * 8;
    *(uint4*)(dh + cb) = oh.u[0];
    *(uint4*)(dh + cb + 8) = oh.u[1];
    if constexpr (WSPLIT) {
      *(uint4*)(dl + cb) = ol.u[0];
      *(uint4*)(dl + cb + 8) = ol.u[1];
    }
  }
}

// ---------------- router + fp32->(hi,lo) convert; optionally carries wconv blocks ----------------
template <bool WFUSE>
__global__ __launch_bounds__(256) void router_kernel(
    const float* __restrict__ x, const float* __restrict__ rw, float* __restrict__ logits,
    unsigned short* __restrict__ xh, unsigned short* __restrict__ xl,
    const float* __restrict__ wsrc, unsigned short* __restrict__ wdh,
    unsigned short* __restrict__ wdl, int WK, int WN) {
  __shared__ __align__(16) char smem[WFUSE ? 16896 : 8192];
  const int bid = blockIdx.x;
  if constexpr (WFUSE) {
    if (bid >= Tc) {
      wconv_block<true>(wsrc, wdh, wdl, WK, WN, bid - Tc, smem);
      return;
    }
  }
  float(*red)[Ec] = (float(*)[Ec])smem;
  const int t = bid;
  const int tid = threadIdx.x;
  const float* xr = x + (size_t)t * Hc;
  const int h0 = tid * 4;
  const float4 v = *(const float4*)(xr + h0);
  const float f[4] = {v.x, v.y, v.z, v.w};
  unsigned short hs[4], ls[4];
#pragma unroll
  for (int j = 0; j < 4; ++j) {
    hs[j] = f2bf(f[j]);
    ls[j] = f2bf(f[j] - bf2f(hs[j]));
  }
  *(uint2*)(xh + (size_t)t * Hc + h0) =
      uint2{(unsigned)hs[0] | ((unsigned)hs[1] << 16), (unsigned)hs[2] | ((unsigned)hs[3] << 16)};
  *(uint2*)(xl + (size_t)t * Hc + h0) =
      uint2{(unsigned)ls[0] | ((unsigned)ls[1] << 16), (unsigned)ls[2] | ((unsigned)ls[3] << 16)};

  float acc[Ec];
#pragma unroll
  for (int e = 0; e < Ec; ++e) acc[e] = 0.f;
#pragma unroll
  for (int j = 0; j < 4; ++j) {
    const float* w = rw + (size_t)(h0 + j) * Ec;
#pragma unroll
    for (int e = 0; e < Ec; ++e) acc[e] += f[j] * w[e];
  }
#pragma unroll
  for (int e = 0; e < Ec; ++e) red[tid][e] = acc[e];
  __syncthreads();
  for (int s = 128; s > 0; s >>= 1) {
    if (tid < s) {
#pragma unroll
      for (int e = 0; e < Ec; ++e) red[tid][e] += red[tid + s][e];
    }
    __syncthreads();
  }
  if (tid < Ec) logits[(size_t)t * Ec + tid] = red[0][tid];
}

// ---------------- top-2 ----------------
__global__ void topk_kernel(const float* __restrict__ logits, int* __restrict__ cnt,
                            int* __restrict__ tokList, float* __restrict__ wList) {
  const int t = blockIdx.x * blockDim.x + threadIdx.x;
  if (t >= Tc) return;
  float l[Ec];
#pragma unroll
  for (int e = 0; e < Ec; ++e) l[e] = logits[(size_t)t * Ec + e];
  float b0 = -3.4e38f, b1 = -3.4e38f;
  int i0 = 0, i1 = 0;
#pragma unroll
  for (int e = 0; e < Ec; ++e) {
    if (l[e] > b0) { b1 = b0; i1 = i0; b0 = l[e]; i0 = e; }
    else if (l[e] > b1) { b1 = l[e]; i1 = e; }
  }
  const float w0 = 1.f / (1.f + expf(b1 - b0));
  const float w1 = 1.f - w0;
  int p0 = atomicAdd(&cnt[i0], 1);
  tokList[i0 * Tc + p0] = t;
  wList[i0 * Tc + p0] = w0;
  int p1 = atomicAdd(&cnt[i1], 1);
  tokList[i1 * Tc + p1] = t;
  wList[i1 * Tc + p1] = w1;
}

__global__ void offsets_kernel(const int* __restrict__ cnt, int* __restrict__ off) {
  if (threadIdx.x == 0) {
    int s = 0;
    for (int e = 0; e < Ec; ++e) { off[e] = s; s += cnt[e]; }
  }
}

// ---------------- gate_up GEMM: BM=128, BN=64(g)+64(u), BK=32 ----------------
// B frags: direct global->VGPR (staged layout, per-lane contiguous 16B), reg-dbuf.
// A: reg->LDS [128][40] padded, 2-buffer; lgkm-only raw s_barrier.
// Trailing blocks (d >= 4096) run wconv for the NEXT launch's weights.
template <bool SPLIT, bool WFUSE, bool WSPLIT>
__global__ __launch_bounds__(256, SPLIT ? 3 : 4) void gateup_kernel(
    const unsigned short* __restrict__ xh, const unsigned short* __restrict__ xl,
    const unsigned short* __restrict__ gwSh, const unsigned short* __restrict__ gwSl,
    const int* __restrict__ cnt, const int* __restrict__ off,
    const int* __restrict__ tokList, unsigned short* __restrict__ actH,
    unsigned short* __restrict__ actL, const float* __restrict__ wsrc,
    unsigned short* __restrict__ wdh, unsigned short* __restrict__ wdl, int WK, int WN) {
  constexpr int GB = 4096;
  __shared__ __align__(16) char smem[SPLIT ? 40960 : 20480];
  const int d = blockIdx.x;
  if constexpr (WFUSE) {
    if (d >= GB) {
      wconv_block<WSPLIT>(wsrc, wdh, wdl, WK, WN, d - GB, smem);
      return;
    }
  }
  // bijective chunked XCD swizzle over the GEMM sub-grid (GB % 8 == 0)
  const int lid = (d & 7) * (GB >> 3) + (d >> 3);
  const int mi = lid & 15;
  const int e = (lid >> 4) & 7;
  const int nb = lid >> 7;  // 0..31
  const int M = cnt[e];
  const int m0 = mi * 128;
  if (m0 >= M) return;
  const int tid = threadIdx.x;
  const int wv = tid >> 6, l64 = tid & 63;
  const int q = l64 >> 4, mr = l64 & 15;
  const int nc = wv * 16 + mr;

  unsigned short* sAh = (unsigned short*)smem;                         // [2][5120]
  unsigned short* sAl = (unsigned short*)(SPLIT ? smem + 20480 : smem);

  const size_t fragoff = (size_t)(q * 64 + nc) * 8;
  const size_t gBase = (((size_t)e * 64 + nb) * 32) * 2048 + fragoff;
  const size_t uBase = (((size_t)e * 64 + nb + 32) * 32) * 2048 + fragoff;

  const int ar = tid >> 2, ak = (tid & 3) * 8;
  int r0 = m0 + ar;      if (r0 >= M) r0 = M - 1;
  int r1 = m0 + 64 + ar; if (r1 >= M) r1 = M - 1;
  const size_t a0o = (size_t)tokList[e * Tc + r0] * Hc + ak;
  const size_t a1o = (size_t)tokList[e * Tc + r1] * Hc + ak;

  f32x4 accg[8], accu[8];
#pragma unroll
  for (int i = 0; i < 8; ++i) {
    accg[i] = f32x4{0.f, 0.f, 0.f, 0.f};
    accu[i] = f32x4{0.f, 0.f, 0.f, 0.f};
  }

  uint4 paA0h{}, paA1h{}, paA0l{}, paA1l{};
  uint4 paB0h{}, paB1h{}, paB0l{}, paB1l{};
  bf16x8 bcAgh{}, bcAuh{}, bcAgl{}, bcAul{};
  bf16x8 bcBgh{}, bcBuh{}, bcBgl{}, bcBul{};

  // ---- prologue: A(0) -> LDS[0]; B(0) -> regs(A); A(1) -> regs(A)
  paA0h = *(const uint4*)(xh + a0o);
  paA1h = *(const uint4*)(xh + a1o);
  if constexpr (SPLIT) {
    paA0l = *(const uint4*)(xl + a0o);
    paA1l = *(const uint4*)(xl + a1o);
  }
  *(uint4*)&sAh[ar * 40 + ak] = paA0h;
  *(uint4*)&sAh[(ar + 64) * 40 + ak] = paA1h;
  if constexpr (SPLIT) {
    *(uint4*)&sAl[ar * 40 + ak] = paA0l;
    *(uint4*)&sAl[(ar + 64) * 40 + ak] = paA1l;
  }
  bcAgh = ldfrag(gwSh + gBase);
  bcAuh = ldfrag(gwSh + uBase);
  if constexpr (SPLIT) {
    bcAgl = ldfrag(gwSl + gBase);
    bcAul = ldfrag(gwSl + uBase);
  }
  paA0h = *(const uint4*)(xh + a0o + 32);
  paA1h = *(const uint4*)(xh + a1o + 32);
  if constexpr (SPLIT) {
    paA0l = *(const uint4*)(xl + a0o + 32);
    paA1l = *(const uint4*)(xl + a1o + 32);
  }
  asm volatile("s_waitcnt lgkmcnt(0)" ::: "memory");
  __builtin_amdgcn_s_barrier();

#define GU_STEP(T, CUR, NX, PA0H, PA1H, PA0L, PA1L, PN0H, PN1H, PN0L, PN1L,             \
                BCGH, BCUH, BCGL, BCUL, BNGH, BNUH, BNGL, BNUL)                         \
  {                                                                                     \
    if ((T) + 1 < 32) {                                                                 \
      BNGH = ldfrag(gwSh + gBase + (size_t)((T) + 1) * 2048);                           \
      BNUH = ldfrag(gwSh + uBase + (size_t)((T) + 1) * 2048);                           \
      if constexpr (SPLIT) {                                                            \
        BNGL = ldfrag(gwSl + gBase + (size_t)((T) + 1) * 2048);                         \
        BNUL = ldfrag(gwSl + uBase + (size_t)((T) + 1) * 2048);                         \
      }                                                                                 \
    }                                                                                   \
    if ((T) + 2 < 32) {                                                                 \
      PN0H = *(const uint4*)(xh + a0o + ((T) + 2) * 32);                                \
      PN1H = *(const uint4*)(xh + a1o + ((T) + 2) * 32);                                \
      if constexpr (SPLIT) {                                                            \
        PN0L = *(const uint4*)(xl + a0o + ((T) + 2) * 32);                              \
        PN1L = *(const uint4*)(xl + a1o + ((T) + 2) * 32);                              \
      }                                                                                 \
    }                                                                                   \
    if ((T) + 1 < 32) {                                                                 \
      *(uint4*)&sAh[(NX) * 5120 + ar * 40 + ak] = PA0H;                                 \
      *(uint4*)&sAh[(NX) * 5120 + (ar + 64) * 40 + ak] = PA1H;                          \
      if constexpr (SPLIT) {                                                            \
        *(uint4*)&sAl[(NX) * 5120 + ar * 40 + ak] = PA0L;                               \
        *(uint4*)&sAl[(NX) * 5120 + (ar + 64) * 40 + ak] = PA1L;                        \
      }                                                                                 \
    }                                                                                   \
    __builtin_amdgcn_s_setprio(1);                                                      \
    _Pragma("unroll")                                                                   \
    for (int mt = 0; mt < 8; ++mt) {                                                    \
      const bf16x8 ah = ldfrag(&sAh[(CUR) * 5120 + (mt * 16 + mr) * 40 + q * 8]);       \
      accg[mt] = __builtin_amdgcn_mfma_f32_16x16x32_bf16(ah, BCGH, accg[mt], 0, 0, 0);  \
      accu[mt] = __builtin_amdgcn_mfma_f32_16x16x32_bf16(ah, BCUH, accu[mt], 0, 0, 0);  \
      if constexpr (SPLIT) {                                                            \
        const bf16x8 alr = ldfrag(&sAl[(CUR) * 5120 + (mt * 16 + mr) * 40 + q * 8]);    \
        accg[mt] = __builtin_amdgcn_mfma_f32_16x16x32_bf16(ah, BCGL, accg[mt], 0, 0, 0);\
        accg[mt] = __builtin_amdgcn_mfma_f32_16x16x32_bf16(alr, BCGH, accg[mt], 0, 0, 0);\
        accu[mt] = __builtin_amdgcn_mfma_f32_16x16x32_bf16(ah, BCUL, accu[mt], 0, 0, 0);\
        accu[mt] = __builtin_amdgcn_mfma_f32_16x16x32_bf16(alr, BCUH, accu[mt], 0, 0, 0);\
      }                                                                                 \
    }                                                                                   \
    __builtin_amdgcn_s_setprio(0);                                                      \
    if ((T) < 31) {                                                                     \
      asm volatile("s_waitcnt lgkmcnt(0)" ::: "memory");                                \
      __builtin_amdgcn_s_barrier();                                                     \
    }                                                                                   \
  }

  for (int t = 0; t < 32; t += 2) {
    GU_STEP(t, 0, 1, paA0h, paA1h, paA0l, paA1l, paB0h, paB1h, paB0l, paB1l,
            bcAgh, bcAuh, bcAgl, bcAul, bcBgh, bcBuh, bcBgl, bcBul)
    GU_STEP(t + 1, 1, 0, paB0h, paB1h, paB0l, paB1l, paA0h, paA1h, paA0l, paA1l,
            bcBgh, bcBuh, bcBgl, bcBul, bcAgh, bcAuh, bcAgl, bcAul)
  }
#undef GU_STEP

  const int valid = M - m0;
  const int rowbase = off[e] + m0;
#pragma unroll
  for (int mt = 0; mt < 8; ++mt) {
#pragma unroll
    for (int r = 0; r < 4; ++r) {
      const int row = mt * 16 + q * 4 + r;  // C/D: row=(lane>>4)*4+reg, col=lane&15 (m89)
      if (row < valid) {
        const float g = accg[mt][r];
        const float u = accu[mt][r];
        const float a = (g / (1.f + expf(-g))) * u;
        const size_t idx = (size_t)(rowbase + row) * Ic + (nb * 64 + nc);
        const unsigned short h = f2bf(a);
        actH[idx] = h;
        if constexpr (SPLIT) actL[idx] = f2bf(a - bf2f(h));
      }
    }
  }
}

// ---------------- down GEMM: BM=128, BN=64, K=Ic, same structure ----------------
template <bool SPLIT, bool WFUSE, bool WSPLIT>
__global__ __launch_bounds__(256, 4) void down_kernel(
    const unsigned short* __restrict__ actH, const unsigned short* __restrict__ actL,
    const unsigned short* __restrict__ dwSh, const unsigned short* __restrict__ dwSl,
    const int* __restrict__ cnt, const int* __restrict__ off,
    const int* __restrict__ tokList, const float* __restrict__ wList,
    float* __restrict__ out, const float* __restrict__ wsrc,
    unsigned short* __restrict__ wdh, unsigned short* __restrict__ wdl, int WK, int WN) {
  constexpr int GB = 2048;
  __shared__ __align__(16) char smem[SPLIT ? 40960 : 20480];
  __shared__ int sTok[128];
  __shared__ float sW[128];
  const int d = blockIdx.x;
  if constexpr (WFUSE) {
    if (d >= GB) {
      wconv_block<WSPLIT>(wsrc, wdh, wdl, WK, WN, d - GB, smem);
      return;
    }
  }
  const int lid = (d & 7) * (GB >> 3) + (d >> 3);
  const int mi = lid & 15;
  const int e = (lid >> 4) & 7;
  const int nb = lid >> 7;  // 0..15
  const int M = cnt[e];
  const int m0 = mi * 128;
  if (m0 >= M) return;
  const int tid = threadIdx.x;
  const int wv = tid >> 6, l64 = tid & 63;
  const int q = l64 >> 4, mr = l64 & 15;
  const int nc = wv * 16 + mr;

  unsigned short* sAh = (unsigned short*)smem;
  unsigned short* sAl = (unsigned short*)(SPLIT ? smem + 20480 : smem);

  if (tid < 128) {
    int r = m0 + tid;
    int rc = r < M ? r : M - 1;
    sTok[tid] = tokList[e * Tc + rc];
    sW[tid] = wList[e * Tc + rc];
  }

  const size_t fragoff = (size_t)(q * 64 + nc) * 8;
  const size_t bBase = (((size_t)e * 16 + nb) * 64) * 2048 + fragoff;
  const int offE = off[e];

  const int ar = tid >> 2, ak = (tid & 3) * 8;
  int r0 = m0 + ar;      if (r0 >= M) r0 = M - 1;
  int r1 = m0 + 64 + ar; if (r1 >= M) r1 = M - 1;
  const size_t a0o = (size_t)(offE + r0) * Ic + ak;
  const size_t a1o = (size_t)(offE + r1) * Ic + ak;

  f32x4 acc[8];
#pragma unroll
  for (int i = 0; i < 8; ++i) acc[i] = f32x4{0.f, 0.f, 0.f, 0.f};

  uint4 paA0h{}, paA1h{}, paA0l{}, paA1l{};
  uint4 paB0h{}, paB1h{}, paB0l{}, paB1l{};
  bf16x8 bcAh{}, bcAl{}, bcBh{}, bcBl{};

  paA0h = *(const uint4*)(actH + a0o);
  paA1h = *(const uint4*)(actH + a1o);
  if constexpr (SPLIT) {
    paA0l = *(const uint4*)(actL + a0o);
    paA1l = *(const uint4*)(actL + a1o);
  }
  *(uint4*)&sAh[ar * 40 + ak] = paA0h;
  *(uint4*)&sAh[(ar + 64) * 40 + ak] = paA1h;
  if constexpr (SPLIT) {
    *(uint4*)&sAl[ar * 40 + ak] = paA0l;
    *(uint4*)&sAl[(ar + 64) * 40 + ak] = paA1l;
  }
  bcAh = ldfrag(dwSh + bBase);
  if constexpr (SPLIT) bcAl = ldfrag(dwSl + bBase);
  paA0h = *(const uint4*)(actH + a0o + 32);
  paA1h = *(const uint4*)(actH + a1o + 32);
  if constexpr (SPLIT) {
    paA0l = *(const uint4*)(actL + a0o + 32);
    paA1l = *(const uint4*)(actL + a1o + 32);
  }
  asm volatile("s_waitcnt lgkmcnt(0)" ::: "memory");
  __builtin_amdgcn_s_barrier();

#define DN_STEP(T, CUR, NX, PA0H, PA1H, PA0L, PA1L, PN0H, PN1H, PN0L, PN1L,             \
                BCH, BCL, BNH, BNL)                                                     \
  {                                                                                     \
    if ((T) + 1 < 64) {                                                                 \
      BNH = ldfrag(dwSh + bBase + (size_t)((T) + 1) * 2048);                            \
      if constexpr (SPLIT) BNL = ldfrag(dwSl + bBase + (size_t)((T) + 1) * 2048);       \
    }                                                                                   \
    if ((T) + 2 < 64) {                                                                 \
      PN0H = *(const uint4*)(actH + a0o + ((T) + 2) * 32);                              \
      PN1H = *(const uint4*)(actH + a1o + ((T) + 2) * 32);                              \
      if constexpr (SPLIT) {                                                            \
        PN0L = *(const uint4*)(actL + a0o + ((T) + 2) * 32);                            \
        PN1L = *(const uint4*)(actL + a1o + ((T) + 2) * 32);                            \
      }                                                                                 \
    }                                                                                   \
    if ((T) + 1 < 64) {                                                                 \
      *(uint4*)&sAh[(NX) * 5120 + ar * 40 + ak] = PA0H;                                 \
      *(uint4*)&sAh[(NX) * 5120 + (ar + 64) * 40 + ak] = PA1H;                          \
      if constexpr (SPLIT) {                                                            \
        *(uint4*)&sAl[(NX) * 5120 + ar * 40 + ak] = PA0L;                               \
        *(uint4*)&sAl[(NX) * 5120 + (ar + 64) * 40 + ak] = PA1L;                        \
      }                                                                                 \
    }                                                                                   \
    __builtin_amdgcn_s_setprio(1);                                                      \
    _Pragma("unroll")                                                                   \
    for (int mt = 0; mt < 8; ++mt) {                                                    \
      const bf16x8 ah = ldfrag(&sAh[(CUR) * 5120 + (mt * 16 + mr) * 40 + q * 8]);       \
      acc[mt] = __builtin_amdgcn_mfma_f32_16x16x32_bf16(ah, BCH, acc[mt], 0, 0, 0);     \
      if constexpr (SPLIT) {                                                            \
        const bf16x8 alr = ldfrag(&sAl[(CUR) * 5120 + (mt * 16 + mr) * 40 + q * 8]);    \
        acc[mt] = __builtin_amdgcn_mfma_f32_16x16x32_bf16(ah, BCL, acc[mt], 0, 0, 0);   \
        acc[mt] = __builtin_amdgcn_mfma_f32_16x16x32_bf16(alr, BCH, acc[mt], 0, 0, 0);  \
      }                                                                                 \
    }                                                                                   \
    __builtin_amdgcn_s_setprio(0);                                                      \
    if ((T) < 63) {                                                                     \
      asm volatile("s_waitcnt lgkmcnt(0)" ::: "memory");                                \
      __builtin_amdgcn_s_barrier();                                                     \
    }                                                                                   \
  }

  for (int t = 0; t < 64; t += 2) {
    DN_STEP(t, 0, 1, paA0h, paA1h, paA0l, paA1l, paB0h, paB1h, paB0l, paB1l,
            bcAh, bcAl, bcBh, bcBl)
    DN_STEP(t + 1, 1, 0, paB0h, paB1h, paB0l, paB1l, paA0h, paA1h, paA0l, paA1l,
            bcBh, bcBl, bcAh, bcAl)
  }
#undef DN_STEP

  const int valid = M - m0;
#pragma unroll
  for (int mt = 0; mt < 8; ++mt) {
#pragma unroll
    for (int r = 0; r < 4; ++r) {
      const int row = mt * 16 + q * 4 + r;
      if (row < valid) {
        atomicAdd(&out[(size_t)sTok[row] * Hc + (nb * 64 + nc)], sW[row] * acc[mt][r]);
      }
    }
  }
}

// ---------------- host ----------------
extern "C" void kernel_launch(void* const* d_in, const int* in_sizes, int n_in, void* d_out,
                              int out_size, void* d_ws, size_t ws_size, hipStream_t stream) {
  const float* x_in = (const float*)d_in[0];
  const float* rw = (const float*)d_in[1];
  const float* guw = (const float*)d_in[2];
  const float* dnw = (const float*)d_in[3];
  float* out = (float*)d_out;
  float* logits_base = out + (size_t)Tc * Hc;

  uint8_t* w = (uint8_t*)d_ws;
  float* x1 = (float*)w;                    w += (size_t)Tc * Hc * 4;
  unsigned short* xh = (unsigned short*)w;  w += (size_t)Tc * Hc * 2;
  unsigned short* xl = (unsigned short*)w;  w += (size_t)Tc * Hc * 2;
  unsigned short* actH = (unsigned short*)w; w += (size_t)Tc * 2 * Ic * 2;
  unsigned short* actL = (unsigned short*)w; w += (size_t)Tc * 2 * Ic * 2;
  int* tokList = (int*)w;                   w += (size_t)Ec * Tc * 4;
  float* wList = (float*)w;                 w += (size_t)Ec * Tc * 4;
  int* cnt0 = (int*)w;                      w += 64;
  int* cnt1 = (int*)w;                      w += 64;
  int* off = (int*)w;                       w += 64;
  // ping-pong staged-weight buffers: A = gate_up sized, B = down sized
  unsigned short* wAh = (unsigned short*)w; w += (size_t)Ec * 2 * Ic * Hc * 2;
  unsigned short* wAl = (unsigned short*)w; w += (size_t)Ec * 2 * Ic * Hc * 2;
  unsigned short* wBh = (unsigned short*)w; w += (size_t)Ec * Ic * Hc * 2;
  unsigned short* wBl = (unsigned short*)w; w += (size_t)Ec * Ic * Hc * 2;

  hipMemsetAsync(cnt0, 0, 192, stream);
  hipMemsetAsync(x1, 0, (size_t)Tc * Hc * 4, stream);
  hipMemsetAsync(out, 0, (size_t)Tc * Hc * 4, stream);

  const float* rw1 = rw + (size_t)Hc * Ec;
  const float* guw1 = guw + (size_t)Ec * Hc * 2 * Ic;
  const float* dnw1 = dnw + (size_t)Ec * Ic * Hc;

  // ---- layer 0 (split-bf16) ----
  // router carries wconv(gu-L0 -> wA, split); 2048 + 64*16*8 blocks
  router_kernel<true><<<Tc + 8192, 256, 0, stream>>>(x_in, rw, logits_base, xh, xl,
                                                     guw, wAh, wAl, Hc, 2 * Ic);
  topk_kernel<<<Tc / 256, 256, 0, stream>>>(logits_base, cnt0, tokList, wList);
  offsets_kernel<<<1, 64, 0, stream>>>(cnt0, off);
  // gateup reads wA; carries wconv(dn-L0 -> wB, split); 4096 + 16*32*8 blocks
  gateup_kernel<true, true, true><<<4096 + 4096, 256, 0, stream>>>(
      xh, xl, wAh, wAl, cnt0, off, tokList, actH, actL, dnw, wBh, wBl, Ic, Hc);
  // down reads wB; carries wconv(gu-L1 -> wA, hi-only); 2048 + 8192 blocks
  down_kernel<true, true, false><<<2048 + 8192, 256, 0, stream>>>(
      actH, actL, wBh, wBl, cnt0, off, tokList, wList, x1, guw1, wAh, nullptr, Hc, 2 * Ic);

  // ---- layer 1 (plain bf16) ----
  router_kernel<false><<<Tc, 256, 0, stream>>>(x1, rw1, logits_base + (size_t)Tc * Ec, xh, xl,
                                               nullptr, nullptr, nullptr, 0, 0);
  topk_kernel<<<Tc / 256, 256, 0, stream>>>(logits_base + (size_t)Tc * Ec, cnt1, tokList, wList);
  offsets_kernel<<<1, 64, 0, stream>>>(cnt1, off);
  // gateup reads wA; carries wconv(dn-L1 -> wB, hi-only)
  gateup_kernel<false, true, false><<<4096 + 4096, 256, 0, stream>>>(
      xh, xl, wAh, wAl, cnt1, off, tokList, actH, actL, dnw1, wBh, nullptr, Ic, Hc);
  down_kernel<false, false, false><<<2048, 256, 0, stream>>>(
      actH, actL, wBh, wBl, cnt1, off, tokList, wList, out, nullptr, nullptr, nullptr, 0, 0);
}